// Round 27
// baseline (527.800 us; speedup 1.0000x reference)
//
#include <hip/hip_runtime.h>
#include <cstdint>
#include <cstddef>

// GAAPModelB on MI355X: bf16-MFMA GEMM stack + CSR gather aggregation.
// N=100000, E=800000, IN=128, H=256, G=512.
// R27: chunk GEMMs BM 64->128 (BK=32, BN=256). 32 MFMA/step/wave (2x
// barrier amortization), 48KB LDS dbuf (~3 blocks/CU), grids halve to
// near-single-pass (782 vs 1024-4/CU capacity). K-order unchanged ->
// bit-identical accumulation. gemm64 epilogue stages 64 rows x2.

#define NN 100000
#define NE 800000
#define CR 100000  // single chunk
#define NB1 98     // ceil(100000/1024) scan blocks
#define CNTB 3125  // count-role blocks (1 in 5 of first 15625)
#define XCVB 12500 // x-cvt-role blocks
#define NJOB 11
#define WCVB (NJOB * 32)
#define EMB_MB 782 // ceil(100000/128)

typedef __attribute__((ext_vector_type(8))) short short8;
typedef __attribute__((ext_vector_type(8))) unsigned short ushort8;
typedef __attribute__((ext_vector_type(4))) float f32x4;

__device__ __forceinline__ float b2f(ushort u) {
  union { unsigned u; float f; } v; v.u = ((unsigned)u) << 16; return v.f;
}
__device__ __forceinline__ ushort f2b(float f) {
  union { float f; unsigned u; } v; v.f = f;
  unsigned r = v.u + 0x7FFFu + ((v.u >> 16) & 1u);
  return (ushort)(r >> 16);
}
__device__ __forceinline__ void gl_lds16(const void* g, void* l) {
  __builtin_amdgcn_global_load_lds((const __attribute__((address_space(1))) void*)g,
                                   (__attribute__((address_space(3))) void*)l, 16, 0, 0);
}

// ------------------------------ utility ------------------------------
// block 0: detect int64 edge layout; blocks 1..: zero cnt
__global__ void zero_detect_k(const int* __restrict__ ei, int* __restrict__ flag,
                              int* __restrict__ cnt, int n) {
  if (blockIdx.x == 0) {
    __shared__ int ok;
    int t = threadIdx.x;
    if (t == 0) ok = 1;
    __syncthreads();
    if (ei[2 * t + 1] != 0) ok = 0;
    __syncthreads();
    if (t == 0) *flag = ok;
  } else {
    int i = (blockIdx.x - 1) * 256 + threadIdx.x;
    if (i < n) cnt[i] = 0;
  }
}

struct CvtJobs {
  const float* src[NJOB];
  ushort* dst[NJOB];
  int R[NJOB], C[NJOB], off[NJOB], tr[NJOB];
  float sc[NJOB];
};

// ------------------------------ CSR build + conversions (3 roles, interleaved) ------------------------------
__global__ void count_cvt_k(const int* __restrict__ ei, const int* __restrict__ flag,
                            int* __restrict__ cnt, int* __restrict__ loc,
                            const float* __restrict__ x, ushort* __restrict__ xb,
                            int E, int n4, CvtJobs jb) {
  int b = blockIdx.x;
  if (b < CNTB + XCVB) {
    int q = b / 5;
    if (b - q * 5 == 0) {
      int i = q * 256 + threadIdx.x;
      if (i >= E) return;
      const bool i64 = (*flag != 0);
      unsigned d = (unsigned)(i64 ? ei[2 * E + 2 * i] : ei[E + i]);
      int p = -1;
      if (d < NN) p = atomicAdd(&cnt[d], 1);
      loc[i] = p;
    } else {
      int i = (b - q - 1) * 256 + threadIdx.x;
      if (i < n4) {
        float4 v = ((const float4*)x)[i];
        ushort4 o; o.x = f2b(v.x); o.y = f2b(v.y); o.z = f2b(v.z); o.w = f2b(v.w);
        ((ushort4*)xb)[i] = o;
      }
    }
  } else {
    int wb = b - CNTB - XCVB;
    int j = wb >> 5;            // job
    int ib = wb & 31;           // inner block
    const int Cj = jb.C[j], Rj = jb.R[j];
    const float sc = jb.sc[j];
    const int n = Rj * Cj;
    if (jb.tr[j]) {
      for (int i = ib * 256 + threadIdx.x; i < n; i += 32 * 256) {
        int c = i / Rj, r = i - c * Rj;
        jb.dst[j][i] = f2b(jb.src[j][(size_t)(jb.off[j] + r) * Cj + c] * sc);
      }
    } else {
      for (int i = ib * 256 + threadIdx.x; i < n; i += 32 * 256)
        jb.dst[j][i] = f2b(jb.src[j][i] * sc);
    }
  }
}

// ------------------------------ scan bodies ------------------------------
__device__ __forceinline__ void scan1_body(const int* __restrict__ cnt,
                                           int* __restrict__ rowptr,
                                           int* __restrict__ bsum, int n, int b,
                                           char* smem) {
  int* ls = (int*)smem;
  const int t = threadIdx.x;
  const int base = b * 1024 + t * 4;
  int v[4]; int s = 0;
#pragma unroll
  for (int j = 0; j < 4; ++j) { int i = base + j; v[j] = (i < n) ? cnt[i] : 0; s += v[j]; }
  ls[t] = s; __syncthreads();
  int x = s;
  for (int o = 1; o < 256; o <<= 1) {
    int a = (t >= o) ? ls[t - o] : 0; __syncthreads();
    x += a; ls[t] = x; __syncthreads();
  }
  int run = x - s;
#pragma unroll
  for (int j = 0; j < 4; ++j) { run += v[j]; int i = base + j; if (i < n) rowptr[i + 1] = run; }
  if (t == 255) bsum[b] = x;
}

__device__ __forceinline__ void scan2_body(const int* __restrict__ bsum,
                                           int* __restrict__ boff, int nb,
                                           char* smem) {
  int* ls = (int*)smem;
  int t = threadIdx.x;
  int v = (t < 128 && t < nb) ? bsum[t] : 0;
  if (t < 128) ls[t] = v;
  __syncthreads();
  int x = v;
  for (int o = 1; o < 128; o <<= 1) {
    int a = (t < 128 && t >= o) ? ls[t - o] : 0;
    __syncthreads();
    x += a;
    if (t < 128) ls[t] = x;
    __syncthreads();
  }
  if (t < 128 && t < nb) boff[t] = x - v;
}

__device__ __forceinline__ void sbias_body(const float* __restrict__ bq,
                                           const ushort* __restrict__ Kmat,
                                           float* __restrict__ sbias, int blk) {
  int g = blk * 4 + (threadIdx.x >> 6);
  int lane = threadIdx.x & 63;
  if (g >= 512) return;
  ushort4 kv = ((const ushort4*)(Kmat + (size_t)g * 256))[lane];
  float4 bv = ((const float4*)bq)[lane];
  float p = b2f(kv.x) * bv.x + b2f(kv.y) * bv.y + b2f(kv.z) * bv.z + b2f(kv.w) * bv.w;
  for (int off = 32; off; off >>= 1) p += __shfl_xor(p, off);
  if (lane == 0) sbias[g] = p * 0.0625f;
}

__global__ void scan3_k(int* __restrict__ rowptr, const int* __restrict__ boff, int n) {
  int i = blockIdx.x * 256 + threadIdx.x;
  if (i == 0) rowptr[0] = 0;
  if (i < n) rowptr[i + 1] += boff[i >> 10];
}

// atomic-free fill: position = rowptr[d] + loc[i]
__global__ void fill_edges_k(const int* __restrict__ ei, const int* __restrict__ flag,
                             const int* __restrict__ rowptr, const int* __restrict__ loc,
                             int* __restrict__ eidx, int E) {
  int i = blockIdx.x * 256 + threadIdx.x;
  if (i >= E) return;
  const bool i64 = (*flag != 0);
  unsigned s = (unsigned)(i64 ? ei[2 * i] : ei[i]);
  unsigned d = (unsigned)(i64 ? ei[2 * E + 2 * i] : ei[E + i]);
  int lc = loc[i];
  if (d < NN && s < NN && lc >= 0) {
    unsigned p = (unsigned)(rowptr[d] + lc);
    if (p < (unsigned)E) eidx[p] = (int)s;
  }
}

// ------------------------------ aggregation ------------------------------
__global__ void agg64_k(const ushort* __restrict__ X, const int* __restrict__ rowptr,
                        const int* __restrict__ eidx, ushort* __restrict__ mean,
                        int r0, int M) {
  int nl = blockIdx.x * 4 + (threadIdx.x >> 6);
  int l = threadIdx.x & 63;
  int e4 = l >> 4;      // edge slot 0..3
  int d4 = l & 15;      // dim group (4 dims)
  if (nl >= M) return;
  int node = r0 + nl;
  int s = rowptr[node], e = rowptr[node + 1];
  float a0 = 0.f, a1 = 0.f, a2 = 0.f, a3 = 0.f;
  for (int i = s + e4; i < e; i += 4) {
    unsigned sc = (unsigned)eidx[i];
    if (sc < NN) {
      ushort4 v = ((const ushort4*)(X + (size_t)sc * 64))[d4];
      a0 += b2f(v.x); a1 += b2f(v.y); a2 += b2f(v.z); a3 += b2f(v.w);
    }
  }
  a0 += __shfl_xor(a0, 16); a0 += __shfl_xor(a0, 32);
  a1 += __shfl_xor(a1, 16); a1 += __shfl_xor(a1, 32);
  a2 += __shfl_xor(a2, 16); a2 += __shfl_xor(a2, 32);
  a3 += __shfl_xor(a3, 16); a3 += __shfl_xor(a3, 32);
  if (e4 == 0) {
    float inv = 1.f / (float)max(e - s, 1);
    ushort4 o; o.x = f2b(a0 * inv); o.y = f2b(a1 * inv); o.z = f2b(a2 * inv); o.w = f2b(a3 * inv);
    ((ushort4*)(mean + (size_t)nl * 64))[d4] = o;
  }
}

__global__ void agg256_k(const ushort* __restrict__ X, const int* __restrict__ rowptr,
                         const int* __restrict__ eidx, ushort* __restrict__ mean,
                         int r0, int M) {
  int nl = blockIdx.x * 4 + (threadIdx.x >> 6);
  int l = threadIdx.x & 63;
  int g = l >> 5;       // edge slot 0..1
  int d = l & 31;       // 8-dim group
  if (nl >= M) return;
  int node = r0 + nl;
  int s = rowptr[node], e = rowptr[node + 1];
  float a[8], c[8];
#pragma unroll
  for (int k = 0; k < 8; ++k) { a[k] = 0.f; c[k] = 0.f; }
  for (int i = s + g; i < e; i += 4) {
    unsigned s0 = (unsigned)eidx[i];
    if (s0 < NN) {
      ushort8 v = *(const ushort8*)(X + (size_t)s0 * 256 + d * 8);
#pragma unroll
      for (int k = 0; k < 8; ++k) a[k] += b2f((ushort)v[k]);
    }
    int i2 = i + 2;
    if (i2 < e) {
      unsigned s1 = (unsigned)eidx[i2];
      if (s1 < NN) {
        ushort8 v = *(const ushort8*)(X + (size_t)s1 * 256 + d * 8);
#pragma unroll
        for (int k = 0; k < 8; ++k) c[k] += b2f((ushort)v[k]);
      }
    }
  }
  float inv = 1.f / (float)max(e - s, 1);
  ushort8 o;
#pragma unroll
  for (int k = 0; k < 8; ++k) {
    float t = a[k] + c[k];
    t += __shfl_xor(t, 32);
    o[k] = (short)f2b(t * inv);
  }
  if (g == 0) *(ushort8*)(mean + (size_t)nl * 256 + d * 8) = o;
}

// ------------------------------ bf16 MFMA GEMM body (2-phase dbuf, BM=128/BK=64) ------------------------------
// used by stage2/stage3 pre-kernels only
template<int BN, bool RELU, bool OUTBF>
__device__ __forceinline__ void gemm_body(
    const ushort* __restrict__ A1, const ushort* __restrict__ BT1, int K1,
    const ushort* __restrict__ A2, const ushort* __restrict__ BT2, int K2,
    const float* __restrict__ bias, void* __restrict__ Cv, int M, int Nc,
    int bmi, int bni, char* smem) {
  constexpr int NR = BN / 32;
  constexpr int WTN = BN / 2;
  constexpr int ABYT = 128 * 64 * 2;
  constexpr int BBYT = BN * 64 * 2;
  constexpr int BUF = ABYT + BBYT;
  constexpr int CP = BN + 8;
  const int tid = threadIdx.x;
  const int l = tid & 63;
  const int w = tid >> 6;
  const int wm = w >> 1, wn = w & 1;
  const int bm = bmi * 128, bn = bni * BN;
  const int r15 = l & 15, g4 = l >> 4;

  const int nt1 = K1 >> 6;
  const int nt2 = A2 ? (K2 >> 6) : 0;
  const int nt = nt1 + nt2;

  auto STAGE = [&](int buf, int t) {
    const ushort* A = (t < nt1) ? A1 : A2;
    const ushort* BT = (t < nt1) ? BT1 : BT2;
    const int K = (t < nt1) ? K1 : K2;
    const int k0 = ((t < nt1) ? t : t - nt1) << 6;
    char* As = smem + buf * BUF;
    char* Bs = As + ABYT;
#pragma unroll
    for (int p = 0; p < 4; ++p) {
      int idx = tid + p * 256;
      int row = idx >> 3, slot = idx & 7;
      int kb = slot ^ (row & 7);
      int grow = bm + row; if (grow >= M) grow = M - 1;
      gl_lds16(A + (size_t)grow * K + k0 + kb * 8, As + idx * 16);
    }
#pragma unroll
    for (int p = 0; p < BN / 32; ++p) {
      int idx = tid + p * 256;
      int row = idx >> 3, slot = idx & 7;
      int kb = slot ^ (row & 7);
      gl_lds16(BT + (size_t)(bn + row) * K + k0 + kb * 8, Bs + idx * 16);
    }
  };

  f32x4 acc[4][NR];
  const f32x4 zz = {0.f, 0.f, 0.f, 0.f};
#pragma unroll
  for (int m = 0; m < 4; ++m)
#pragma unroll
    for (int n = 0; n < NR; ++n) acc[m][n] = zz;

  STAGE(0, 0);
  int cur = 0;
  for (int t = 0; t < nt; ++t) {
    __syncthreads();
    if (t + 1 < nt) STAGE(cur ^ 1, t + 1);
    const char* As = smem + cur * BUF;
    const char* Bs = As + ABYT;
#pragma unroll
    for (int s = 0; s < 2; ++s) {
      short8 a[4], b[NR];
      const int slotx = (((s * 4 + g4) ^ (r15 & 7)) << 4);
#pragma unroll
      for (int m = 0; m < 4; ++m) {
        int row = wm * 64 + m * 16 + r15;
        a[m] = *(const short8*)(As + row * 128 + slotx);
      }
#pragma unroll
      for (int n = 0; n < NR; ++n) {
        int row = wn * WTN + n * 16 + r15;
        b[n] = *(const short8*)(Bs + row * 128 + slotx);
      }
#pragma unroll
      for (int m = 0; m < 4; ++m)
#pragma unroll
        for (int n = 0; n < NR; ++n)
          acc[m][n] = __builtin_amdgcn_mfma_f32_16x16x32_bf16(a[m], b[n], acc[m][n], 0, 0, 0);
    }
    cur ^= 1;
  }
  __syncthreads();
  if (OUTBF) {
    ushort* Cs = (ushort*)smem;
#pragma unroll
    for (int n = 0; n < NR; ++n) {
      int col = wn * WTN + n * 16 + r15;
      float bv = bias ? bias[bn + col] : 0.f;
#pragma unroll
      for (int m = 0; m < 4; ++m) {
#pragma unroll
        for (int j = 0; j < 4; ++j) {
          int row = wm * 64 + m * 16 + g4 * 4 + j;
          float v = acc[m][n][j] + bv;
          if (RELU) v = fmaxf(v, 0.f);
          Cs[row * CP + col] = f2b(v);
        }
      }
    }
    __syncthreads();
    constexpr int C8 = BN / 8;
    for (int it = tid; it < 128 * C8; it += 256) {
      int row = it / C8, c8 = it % C8;
      if (bm + row < M)
        *(ushort8*)((ushort*)Cv + (size_t)(bm + row) * Nc + bn + c8 * 8) =
            *(const ushort8*)(Cs + row * CP + c8 * 8);
    }
  } else {
#pragma unroll
    for (int n = 0; n < NR; ++n) {
      int col = bn + wn * WTN + n * 16 + r15;
      float bv = bias ? bias[col] : 0.f;
#pragma unroll
      for (int m = 0; m < 4; ++m) {
#pragma unroll
        for (int j = 0; j < 4; ++j) {
          int row = bm + wm * 64 + m * 16 + g4 * 4 + j;
          if (row < M) {
            float v = acc[m][n][j] + bv;
            if (RELU) v = fmaxf(v, 0.f);
            ((float*)Cv)[(size_t)row * Nc + col] = v;
          }
        }
      }
    }
  }
}

// ------------------------------ bf16 MFMA GEMM (BM=128, BK=32, BN=256/grid.y, dbuf) ------------------------------
// R27: BM=128 (32 MFMA/step/wave), 48KB LDS. Swizzle kb = slot ^ ((row>>1)&3)
// (conflict-free, R25). Epilogue stages 64 rows at a time (Cs 33.8KB <= 48KB).
template<bool RELU>
__global__ __launch_bounds__(256)
void gemm64_k(const ushort* __restrict__ A1, const ushort* __restrict__ BT1, int K1,
              const ushort* __restrict__ A2, const ushort* __restrict__ BT2, int K2,
              const float* __restrict__ bias, ushort* __restrict__ C, int M, int Nc) {
  constexpr int NR = 8;              // 256 cols / 32
  constexpr int WTN = 128;           // wave col tile
  constexpr int ABYT = 128 * 32 * 2; // 8KB
  constexpr int BBYT = 256 * 32 * 2; // 16KB
  constexpr int BUF = ABYT + BBYT;   // 24KB
  constexpr int CP = 256 + 8;
  __shared__ __align__(16) char smem[2 * BUF];   // 48KB
  const int tid = threadIdx.x;
  const int l = tid & 63;
  const int w = tid >> 6;
  const int wm = w >> 1, wn = w & 1;
  const int bm = blockIdx.x * 128;
  const int bn = blockIdx.y * 256;
  const int r15 = l & 15, g4 = l >> 4;

  const int nt1 = K1 >> 5;
  const int nt2 = A2 ? (K2 >> 5) : 0;
  const int nt = nt1 + nt2;

  auto STAGE = [&](int buf, int t) {
    const ushort* A = (t < nt1) ? A1 : A2;
    const ushort* BT = (t < nt1) ? BT1 : BT2;
    const int K = (t < nt1) ? K1 : K2;
    const int k0 = ((t < nt1) ? t : t - nt1) << 5;
    char* As = smem + buf * BUF;
    char* Bs = As + ABYT;
#pragma unroll
    for (int p = 0; p < 2; ++p) {   // A: 128 rows x 4 slots = 512 chunks
      int idx = tid + p * 256;
      int row = idx >> 2, slot = idx & 3;
      int kb = slot ^ ((row >> 1) & 3);
      int grow = bm + row; if (grow >= M) grow = M - 1;
      gl_lds16(A + (size_t)grow * K + k0 + kb * 8, As + idx * 16);
    }
#pragma unroll
    for (int p = 0; p < 4; ++p) {   // B: 256 rows x 4 slots = 1024 chunks
      int idx = tid + p * 256;
      int row = idx >> 2, slot = idx & 3;
      int kb = slot ^ ((row >> 1) & 3);
      gl_lds16(BT + (size_t)(bn + row) * K + k0 + kb * 8, Bs + idx * 16);
    }
  };

  f32x4 acc[4][NR];
  const f32x4 zz = {0.f, 0.f, 0.f, 0.f};
#pragma unroll
  for (int m = 0; m < 4; ++m)
#pragma unroll
    for (int n = 0; n < NR; ++n) acc[m][n] = zz;

  STAGE(0, 0);
  int cur = 0;
  for (int t = 0; t < nt; ++t) {
    __syncthreads();
    if (t + 1 < nt) STAGE(cur ^ 1, t + 1);
    const char* As = smem + cur * BUF;
    const char* Bs = As + ABYT;
    short8 a[4], b[NR];
#pragma unroll
    for (int m = 0; m < 4; ++m) {
      int row = wm * 64 + m * 16 + r15;
      a[m] = *(const short8*)(As + row * 64 + ((g4 ^ ((row >> 1) & 3)) << 4));
    }
#pragma unroll
    for (int n = 0; n < NR; ++n) {
      int row = wn * WTN + n * 16 + r15;
      b[n] = *(const short8*)(Bs + row * 64 + ((g4 ^ ((row >> 1) & 3)) << 4));
    }
#pragma unroll
    for (int m = 0; m < 4; ++m)
#pragma unroll
      for (int n = 0; n < NR; ++n)
        acc[m][n] = __builtin_amdgcn_mfma_f32_16x16x32_bf16(a[m], b[n], acc[m][n], 0, 0, 0);
    cur ^= 1;
  }
  // epilogue: LDS-staged coalesced bf16 stores, 64 rows per pass
  ushort* Cs = (ushort*)smem;
#pragma unroll
  for (int half = 0; half < 2; ++half) {
    __syncthreads();
    if (wm == half) {
#pragma unroll
      for (int n = 0; n < NR; ++n) {
        int col = wn * WTN + n * 16 + r15;
        float bv = bias ? bias[bn + col] : 0.f;
#pragma unroll
        for (int m = 0; m < 4; ++m) {
#pragma unroll
          for (int j = 0; j < 4; ++j) {
            int row = m * 16 + g4 * 4 + j;
            float v = acc[m][n][j] + bv;
            if (RELU) v = fmaxf(v, 0.f);
            Cs[row * CP + col] = f2b(v);
          }
        }
      }
    }
    __syncthreads();
    for (int it = tid; it < 64 * 32; it += 256) {
      int row = it >> 5, c8 = it & 31;
      int gr = bm + half * 64 + row;
      if (gr < M)
        *(ushort8*)(C + (size_t)gr * Nc + bn + c8 * 8) =
            *(const ushort8*)(Cs + row * CP + c8 * 8);
    }
  }
}

// ------------------------------ stage2: scan1 | Kmat | Vmat | embed ------------------------------
__global__ __launch_bounds__(256)
void stage2_k(const int* __restrict__ cnt, int* __restrict__ rowptr, int* __restrict__ bsum,
              const ushort* __restrict__ gcb, const ushort* __restrict__ WkT,
              const float* __restrict__ bk, ushort* __restrict__ Kmatb,
              const ushort* __restrict__ WvT, const float* __restrict__ bvv,
              ushort* __restrict__ Vmatb,
              const ushort* __restrict__ xb, const ushort* __restrict__ WpT,
              const float* __restrict__ bp, ushort* __restrict__ x_emb) {
  __shared__ __align__(16) char smem[65536];
  int b = blockIdx.x;
  if (b < 8) {
    gemm_body<128, false, true>(gcb, WkT, 256, nullptr, nullptr, 0, bk, Kmatb,
                                512, 256, b & 3, b >> 2, smem);
  } else if (b < 16) {
    int lb = b - 8;
    gemm_body<128, false, true>(gcb, WvT, 256, nullptr, nullptr, 0, bvv, Vmatb,
                                512, 256, lb & 3, lb >> 2, smem);
  } else if (b < 16 + EMB_MB) {
    gemm_body<64, true, true>(xb, WpT, 128, nullptr, nullptr, 0, bp, x_emb,
                              NN, 64, b - 16, 0, smem);
  } else {
    scan1_body(cnt, rowptr, bsum, NN, b - (16 + EMB_MB), smem);
  }
}

// ------------------------------ stage3: scan2 | KWqT | W_pv | sbias ------------------------------
__global__ __launch_bounds__(256)
void stage3_k(const ushort* __restrict__ Kmatb, const ushort* __restrict__ Wqb,
              ushort* __restrict__ KWqT,
              const ushort* __restrict__ Wm1bT, const ushort* __restrict__ Vmatb,
              ushort* __restrict__ W_pvT,
              const float* __restrict__ bq, float* __restrict__ sbias,
              const int* __restrict__ bsum, int* __restrict__ boff) {
  __shared__ __align__(16) char smem[65536];
  int b = blockIdx.x;
  if (b < 8) {
    gemm_body<128, false, true>(Kmatb, Wqb, 256, nullptr, nullptr, 0, nullptr, KWqT,
                                512, 256, b & 3, b >> 2, smem);
  } else if (b < 16) {
    int lb = b - 8;
    gemm_body<128, false, true>(Wm1bT, Vmatb, 256, nullptr, nullptr, 0, nullptr, W_pvT,
                                256, 512, lb & 1, lb >> 1, smem);
  } else if (b < 144) {
    sbias_body(bq, Kmatb, sbias, b - 16);
  } else {
    scan2_body(bsum, boff, NB1, smem);
  }
}

// ------------------------------ fused MLP + output head (BM=128, BK=32, dbuf) ------------------------------
// R27: BM=128. Reduction buffer 2x128x2 f32 = 2KB.
__global__ __launch_bounds__(256)
void mlp_out_k(const ushort* __restrict__ A1, const ushort* __restrict__ BT1, int K1,
               const ushort* __restrict__ A2, const ushort* __restrict__ BT2, int K2,
               const float* __restrict__ bias, const float* __restrict__ Wm2,
               const float* __restrict__ bm2, float* __restrict__ out, int M) {
  constexpr int NR = 8;              // 256 cols / 32
  constexpr int WTN = 128;           // wave col tile
  constexpr int ABYT = 128 * 32 * 2; // 8KB
  constexpr int BBYT = 256 * 32 * 2; // 16KB
  constexpr int BUF = ABYT + BBYT;   // 24KB
  __shared__ __align__(16) char smem[2 * BUF];   // 48KB
  const int tid = threadIdx.x;
  const int l = tid & 63;
  const int w = tid >> 6;
  const int wm = w >> 1, wn = w & 1;
  const int bm = blockIdx.x * 128;
  const int r15 = l & 15, g4 = l >> 4;

  const int nt1 = K1 >> 5;
  const int nt2 = K2 >> 5;
  const int nt = nt1 + nt2;

  auto STAGE = [&](int buf, int t) {
    const ushort* A = (t < nt1) ? A1 : A2;
    const ushort* BT = (t < nt1) ? BT1 : BT2;
    const int K = (t < nt1) ? K1 : K2;
    const int k0 = ((t < nt1) ? t : t - nt1) << 5;
    char* As = smem + buf * BUF;
    char* Bs = As + ABYT;
#pragma unroll
    for (int p = 0; p < 2; ++p) {   // A: 128 rows x 4 slots = 512 chunks
      int idx = tid + p * 256;
      int row = idx >> 2, slot = idx & 3;
      int kb = slot ^ ((row >> 1) & 3);
      int grow = bm + row; if (grow >= M) grow = M - 1;
      gl_lds16(A + (size_t)grow * K + k0 + kb * 8, As + idx * 16);
    }
#pragma unroll
    for (int p = 0; p < 4; ++p) {   // B: 256 rows x 4 slots = 1024 chunks
      int idx = tid + p * 256;
      int row = idx >> 2, slot = idx & 3;
      int kb = slot ^ ((row >> 1) & 3);
      gl_lds16(BT + (size_t)row * K + k0 + kb * 8, Bs + idx * 16);
    }
  };

  f32x4 acc[4][NR];
  const f32x4 zz = {0.f, 0.f, 0.f, 0.f};
#pragma unroll
  for (int m = 0; m < 4; ++m)
#pragma unroll
    for (int n = 0; n < NR; ++n) acc[m][n] = zz;

  STAGE(0, 0);
  int cur = 0;
  for (int t = 0; t < nt; ++t) {
    __syncthreads();
    if (t + 1 < nt) STAGE(cur ^ 1, t + 1);
    const char* As = smem + cur * BUF;
    const char* Bs = As + ABYT;
    short8 a[4], b[NR];
#pragma unroll
    for (int m = 0; m < 4; ++m) {
      int row = wm * 64 + m * 16 + r15;
      a[m] = *(const short8*)(As + row * 64 + ((g4 ^ ((row >> 1) & 3)) << 4));
    }
#pragma unroll
    for (int n = 0; n < NR; ++n) {
      int row = wn * WTN + n * 16 + r15;
      b[n] = *(const short8*)(Bs + row * 64 + ((g4 ^ ((row >> 1) & 3)) << 4));
    }
#pragma unroll
    for (int m = 0; m < 4; ++m)
#pragma unroll
      for (int n = 0; n < NR; ++n)
        acc[m][n] = __builtin_amdgcn_mfma_f32_16x16x32_bf16(a[m], b[n], acc[m][n], 0, 0, 0);
    cur ^= 1;
  }
  __syncthreads();
  float bv[NR], w20[NR], w21[NR];
#pragma unroll
  for (int n = 0; n < NR; ++n) {
    int col = wn * WTN + n * 16 + r15;
    bv[n] = bias[col];
    w20[n] = Wm2[col * 2 + 0];
    w21[n] = Wm2[col * 2 + 1];
  }
  float* red = (float*)smem;   // 2KB
#pragma unroll
  for (int m = 0; m < 4; ++m) {
#pragma unroll
    for (int j = 0; j < 4; ++j) {
      float p0 = 0.f, p1 = 0.f;
#pragma unroll
      for (int n = 0; n < NR; ++n) {
        float v = fmaxf(acc[m][n][j] + bv[n], 0.f);
        p0 += v * w20[n];
        p1 += v * w21[n];
      }
      p0 += __shfl_xor(p0, 1); p1 += __shfl_xor(p1, 1);
      p0 += __shfl_xor(p0, 2); p1 += __shfl_xor(p1, 2);
      p0 += __shfl_xor(p0, 4); p1 += __shfl_xor(p1, 4);
      p0 += __shfl_xor(p0, 8); p1 += __shfl_xor(p1, 8);
      if (r15 == 0) {
        int rl = wm * 64 + m * 16 + g4 * 4 + j;
        red[wn * 256 + rl * 2 + 0] = p0;
        red[wn * 256 + rl * 2 + 1] = p1;
      }
    }
  }
  __syncthreads();
  {
    int rl = tid >> 1, j = tid & 1;   // 256 threads = 128 rows x 2 outputs
    int row = bm + rl;
    if (row < M)
      out[(size_t)row * 2 + j] = red[rl * 2 + j] + red[256 + rl * 2 + j] + bm2[j];
  }
}

// ------------------------------ softmax in place (pre-scaled bf16 logits -> bf16 P) ------------------------------
__global__ void softmax_k(ushort* __restrict__ SP, int M) {
  int row = blockIdx.x * 4 + (threadIdx.x >> 6);
  int lane = threadIdx.x & 63;
  if (row >= M) return;
  ushort4* p = (ushort4*)(SP + (size_t)row * 512);
  ushort4 ua = p[lane];
  ushort4 ub = p[lane + 64];
  float ax = b2f(ua.x), ay = b2f(ua.y), az = b2f(ua.z), aw = b2f(ua.w);
  float bx = b2f(ub.x), by = b2f(ub.y), bz = b2f(ub.z), bw = b2f(ub.w);
  float m = fmaxf(fmaxf(fmaxf(ax, ay), fmaxf(az, aw)),
                  fmaxf(fmaxf(bx, by), fmaxf(bz, bw)));
  for (int off = 32; off; off >>= 1) m = fmaxf(m, __shfl_xor(m, off));
  ax = expf(ax - m); ay = expf(ay - m); az = expf(az - m); aw = expf(aw - m);
  bx = expf(bx - m); by = expf(by - m); bz = expf(bz - m); bw = expf(bw - m);
  float s = ax + ay + az + aw + bx + by + bz + bw;
  for (int off = 32; off; off >>= 1) s += __shfl_xor(s, off);
  float inv = 1.f / s;
  ushort4 oa, ob;
  oa.x = f2b(ax * inv); oa.y = f2b(ay * inv); oa.z = f2b(az * inv); oa.w = f2b(aw * inv);
  ob.x = f2b(bx * inv); ob.y = f2b(by * inv); ob.z = f2b(bz * inv); ob.w = f2b(bw * inv);
  p[lane] = oa;
  p[lane + 64] = ob;
}

// ------------------------------ launch ------------------------------
extern "C" void kernel_launch(void* const* d_in, const int* in_sizes, int n_in,
                              void* d_out, int out_size, void* d_ws, size_t ws_size,
                              hipStream_t stream) {
  const int N = NN, E = NE;
  const float* x   = (const float*)d_in[0];
  const int*   ei  = (const int*)d_in[1];
  const float* gc  = (const float*)d_in[2];
  const float* Wp  = (const float*)d_in[3];
  const float* bp  = (const float*)d_in[4];
  const float* W1l = (const float*)d_in[5];
  const float* b1l = (const float*)d_in[6];
  const float* W1r = (const float*)d_in[7];
  const float* W2l = (const float*)d_in[8];
  const float* b2l = (const float*)d_in[9];
  const float* W2r = (const float*)d_in[10];
  const float* Wq  = (const float*)d_in[11];
  const float* bq  = (const float*)d_in[12];
  const float* Wk  = (const float*)d_in[13];
  const float* bk  = (const float*)d_in[14];
  const float* Wv  = (const float*)d_in[15];
  const float* bv  = (const float*)d_in[16];
  const float* Wm1 = (const float*)d_in[17];
  const float* bm1 = (const float*)d_in[18];
  const float* Wm2 = (const float*)d_in[19];
  const float* bm2 = (const float*)d_in[20];
  float* out = (float*)d_out;

  char* base = (char*)d_ws;
  size_t off = 0;
  auto take = [&](size_t bytes) -> void* {
    void* r = base + off;
    off += (bytes + 255) & ~(size_t)255;
    return r;
  };
  // CSR + misc
  int* cnt    = (int*)take((size_t)N * 4);
  int* rowptr = (int*)take((size_t)(N + 1) * 4);
  int* loc    = (int*)take((size_t)E * 4);
  int* eidx   = (int*)take((size_t)E * 4);
  int* eflag  = (int*)take(256);
  int* bsum   = (int*)take(NB1 * 4);
  int* boff   = (int*)take(NB1 * 4);
  // bf16 weights
  ushort* WpT   = (ushort*)take((size_t)64 * 128 * 2);
  ushort* W1lT  = (ushort*)take((size_t)256 * 64 * 2);
  ushort* W1rT  = (ushort*)take((size_t)256 * 64 * 2);
  ushort* W2lT  = (ushort*)take((size_t)256 * 256 * 2);
  ushort* W2rT  = (ushort*)take((size_t)256 * 256 * 2);
  ushort* WkT   = (ushort*)take((size_t)256 * 256 * 2);
  ushort* WvT   = (ushort*)take((size_t)256 * 256 * 2);
  ushort* Wqb   = (ushort*)take((size_t)256 * 256 * 2);
  ushort* Wm1aT = (ushort*)take((size_t)256 * 256 * 2);
  ushort* Wm1bT = (ushort*)take((size_t)256 * 256 * 2);
  // attention small
  ushort* gcb   = (ushort*)take((size_t)512 * 256 * 2);
  ushort* Kmatb = (ushort*)take((size_t)512 * 256 * 2);
  ushort* Vmatb = (ushort*)take((size_t)512 * 256 * 2);
  ushort* W_pvT = (ushort*)take((size_t)256 * 512 * 2);
  ushort* KWqT  = (ushort*)take((size_t)512 * 256 * 2);
  float*  sbias = (float*)take((size_t)512 * 4);
  // region U (full-size, single chunk): h2 [N*512B] + SP [N*1024B]; mean2
  // aliases SP lower half (dead before S written); pre-loop xb/x_emb/mean1
  // (N*512B total) fit in the h2 segment + start of SP.
  char* U = (char*)take((size_t)N * 1536);
  ushort* h = (ushort*)take((size_t)N * 256 * 2);   // live whole run
  if (off > ws_size) return;

  ushort* xb    = (ushort*)U;                           // N*256B (pre-loop)
  ushort* x_emb = (ushort*)(U + (size_t)N * 256);       // N*128B (pre-loop)
  ushort* mean1 = (ushort*)(U + (size_t)N * 384);       // N*128B (pre-loop)
  ushort* h2_c     = (ushort*)U;                        // N*512B
  ushort* SP_c     = (ushort*)(U + (size_t)N * 512);    // N*1024B (S then P)
  ushort* mean2_c  = SP_c;                              // aliases SP lower half

  const int n4 = N * 128 / 4;
  dim3 thr(256);

  // CvtJobs (Wqb pre-scaled by 1/16 to fold softmax scale)
  CvtJobs jb;
  {
    const float* s_[NJOB] = {gc, Wq, Wp, W1l, W1r, W2l, W2r, Wk, Wv, Wm1, Wm1};
    ushort* d_[NJOB] = {gcb, Wqb, WpT, W1lT, W1rT, W2lT, W2rT, WkT, WvT, Wm1aT, Wm1bT};
    int R_[NJOB] = {512, 256, 128, 64, 64, 256, 256, 256, 256, 256, 256};
    int C_[NJOB] = {256, 256, 64, 256, 256, 256, 256, 256, 256, 256, 256};
    int o_[NJOB] = {0, 0, 0, 0, 0, 0, 0, 0, 0, 0, 256};
    int t_[NJOB] = {0, 0, 1, 1, 1, 1, 1, 1, 1, 1, 1};
    for (int j = 0; j < NJOB; ++j) {
      jb.src[j] = s_[j]; jb.dst[j] = d_[j]; jb.R[j] = R_[j]; jb.C[j] = C_[j];
      jb.off[j] = o_[j]; jb.tr[j] = t_[j]; jb.sc[j] = (j == 1) ? 0.0625f : 1.0f;
    }
  }

  // CSR build + all conversions (count/x-cvt interleaved 1:4, w-cvt tail)
  zero_detect_k<<<1 + (N + 255) / 256, thr, 0, stream>>>(ei, eflag, cnt, N);
  count_cvt_k<<<CNTB + XCVB + WCVB, thr, 0, stream>>>(ei, eflag, cnt, loc, x, xb, E, n4, jb);
  // stage2: scan1 | Kmat | Vmat | embed (all depend only on count_cvt)
  stage2_k<<<16 + EMB_MB + NB1, thr, 0, stream>>>(
      cnt, rowptr, bsum, gcb, WkT, bk, Kmatb, WvT, bv, Vmatb, xb, WpT, bp, x_emb);
  // stage3: scan2 | KWqT | W_pv | sbias (all depend only on stage2)
  stage3_k<<<145, thr, 0, stream>>>(
      Kmatb, Wqb, KWqT, Wm1bT, Vmatb, W_pvT, bq, sbias, bsum, boff);
  scan3_k<<<(N + 255) / 256, thr, 0, stream>>>(rowptr, boff, N);
  fill_edges_k<<<(E + 255) / 256, thr, 0, stream>>>(ei, eflag, rowptr, loc, eidx, E);

  // SAGE1 (BM=128/BK=32 shape)
  agg64_k<<<(N + 3) / 4, thr, 0, stream>>>(x_emb, rowptr, eidx, mean1, 0, N);
  gemm64_k<true><<<dim3((N + 127) / 128, 1), thr, 0, stream>>>(
      mean1, W1lT, 64, x_emb, W1rT, 64, b1l, h, N, 256);

  // single-pass SAGE2 + attention + fused MLP/out (PV folded via W_pv)
  {
    const int CRc = N;
    const int MBc128 = (CRc + 127) / 128;
    agg256_k<<<(CRc + 3) / 4, thr, 0, stream>>>(h, rowptr, eidx, mean2_c, 0, CRc);
    gemm64_k<false><<<dim3(MBc128, 1), thr, 0, stream>>>(
        mean2_c, W2lT, 256, h, W2rT, 256, b2l, h2_c, CRc, 256);
    gemm64_k<false><<<dim3(MBc128, 2), thr, 0, stream>>>(
        h2_c, KWqT, 256, nullptr, nullptr, 0, sbias, SP_c, CRc, 512);
    softmax_k<<<(CRc + 3) / 4, thr, 0, stream>>>(SP_c, CRc);
    mlp_out_k<<<dim3(MBc128, 1), thr, 0, stream>>>(
        h2_c, Wm1aT, 256, SP_c, W_pvT, 512, bm1, Wm2, bm2, out, CRc);
  }
}

// Round 28
// 403.136 us; speedup vs baseline: 1.3092x; 1.3092x over previous
//
#include <hip/hip_runtime.h>
#include <cstdint>
#include <cstddef>

// GAAPModelB on MI355X: bf16-MFMA GEMM stack + CSR gather aggregation.
// N=100000, E=800000, IN=128, H=256, G=512.
// R28 (= R26 + 8-wave GEMM blocks). R27's BM=128-via-registers failed
// (VGPR 140, occupancy 9.5%). Here BM=128 via WAVES: 512-thread blocks,
// two 64-row halves share one B stage. Per-wave code identical to R26
// (acc[2][8], ~84 VGPR). 48KB LDS -> 3 blocks/CU = 24 waves/CU; grid 782
// ~= 768 capacity (1.02 passes); B traffic per work halves. Bit-identical.

#define NN 100000
#define NE 800000
#define CR 100000  // single chunk
#define NB1 98     // ceil(100000/1024) scan blocks
#define CNTB 3125  // count-role blocks (1 in 5 of first 15625)
#define XCVB 12500 // x-cvt-role blocks
#define NJOB 11
#define WCVB (NJOB * 32)
#define EMB_MB 782 // ceil(100000/128)

typedef __attribute__((ext_vector_type(8))) short short8;
typedef __attribute__((ext_vector_type(8))) unsigned short ushort8;
typedef __attribute__((ext_vector_type(4))) float f32x4;

__device__ __forceinline__ float b2f(ushort u) {
  union { unsigned u; float f; } v; v.u = ((unsigned)u) << 16; return v.f;
}
__device__ __forceinline__ ushort f2b(float f) {
  union { float f; unsigned u; } v; v.f = f;
  unsigned r = v.u + 0x7FFFu + ((v.u >> 16) & 1u);
  return (ushort)(r >> 16);
}
__device__ __forceinline__ void gl_lds16(const void* g, void* l) {
  __builtin_amdgcn_global_load_lds((const __attribute__((address_space(1))) void*)g,
                                   (__attribute__((address_space(3))) void*)l, 16, 0, 0);
}

// ------------------------------ utility ------------------------------
// block 0: detect int64 edge layout; blocks 1..: zero cnt
__global__ void zero_detect_k(const int* __restrict__ ei, int* __restrict__ flag,
                              int* __restrict__ cnt, int n) {
  if (blockIdx.x == 0) {
    __shared__ int ok;
    int t = threadIdx.x;
    if (t == 0) ok = 1;
    __syncthreads();
    if (ei[2 * t + 1] != 0) ok = 0;
    __syncthreads();
    if (t == 0) *flag = ok;
  } else {
    int i = (blockIdx.x - 1) * 256 + threadIdx.x;
    if (i < n) cnt[i] = 0;
  }
}

struct CvtJobs {
  const float* src[NJOB];
  ushort* dst[NJOB];
  int R[NJOB], C[NJOB], off[NJOB], tr[NJOB];
  float sc[NJOB];
};

// ------------------------------ CSR build + conversions (3 roles, interleaved) ------------------------------
__global__ void count_cvt_k(const int* __restrict__ ei, const int* __restrict__ flag,
                            int* __restrict__ cnt, int* __restrict__ loc,
                            const float* __restrict__ x, ushort* __restrict__ xb,
                            int E, int n4, CvtJobs jb) {
  int b = blockIdx.x;
  if (b < CNTB + XCVB) {
    int q = b / 5;
    if (b - q * 5 == 0) {
      int i = q * 256 + threadIdx.x;
      if (i >= E) return;
      const bool i64 = (*flag != 0);
      unsigned d = (unsigned)(i64 ? ei[2 * E + 2 * i] : ei[E + i]);
      int p = -1;
      if (d < NN) p = atomicAdd(&cnt[d], 1);
      loc[i] = p;
    } else {
      int i = (b - q - 1) * 256 + threadIdx.x;
      if (i < n4) {
        float4 v = ((const float4*)x)[i];
        ushort4 o; o.x = f2b(v.x); o.y = f2b(v.y); o.z = f2b(v.z); o.w = f2b(v.w);
        ((ushort4*)xb)[i] = o;
      }
    }
  } else {
    int wb = b - CNTB - XCVB;
    int j = wb >> 5;            // job
    int ib = wb & 31;           // inner block
    const int Cj = jb.C[j], Rj = jb.R[j];
    const float sc = jb.sc[j];
    const int n = Rj * Cj;
    if (jb.tr[j]) {
      for (int i = ib * 256 + threadIdx.x; i < n; i += 32 * 256) {
        int c = i / Rj, r = i - c * Rj;
        jb.dst[j][i] = f2b(jb.src[j][(size_t)(jb.off[j] + r) * Cj + c] * sc);
      }
    } else {
      for (int i = ib * 256 + threadIdx.x; i < n; i += 32 * 256)
        jb.dst[j][i] = f2b(jb.src[j][i] * sc);
    }
  }
}

// ------------------------------ scan bodies ------------------------------
__device__ __forceinline__ void scan1_body(const int* __restrict__ cnt,
                                           int* __restrict__ rowptr,
                                           int* __restrict__ bsum, int n, int b,
                                           char* smem) {
  int* ls = (int*)smem;
  const int t = threadIdx.x;
  const int base = b * 1024 + t * 4;
  int v[4]; int s = 0;
#pragma unroll
  for (int j = 0; j < 4; ++j) { int i = base + j; v[j] = (i < n) ? cnt[i] : 0; s += v[j]; }
  ls[t] = s; __syncthreads();
  int x = s;
  for (int o = 1; o < 256; o <<= 1) {
    int a = (t >= o) ? ls[t - o] : 0; __syncthreads();
    x += a; ls[t] = x; __syncthreads();
  }
  int run = x - s;
#pragma unroll
  for (int j = 0; j < 4; ++j) { run += v[j]; int i = base + j; if (i < n) rowptr[i + 1] = run; }
  if (t == 255) bsum[b] = x;
}

__device__ __forceinline__ void scan2_body(const int* __restrict__ bsum,
                                           int* __restrict__ boff, int nb,
                                           char* smem) {
  int* ls = (int*)smem;
  int t = threadIdx.x;
  int v = (t < 128 && t < nb) ? bsum[t] : 0;
  if (t < 128) ls[t] = v;
  __syncthreads();
  int x = v;
  for (int o = 1; o < 128; o <<= 1) {
    int a = (t < 128 && t >= o) ? ls[t - o] : 0;
    __syncthreads();
    x += a;
    if (t < 128) ls[t] = x;
    __syncthreads();
  }
  if (t < 128 && t < nb) boff[t] = x - v;
}

__device__ __forceinline__ void sbias_body(const float* __restrict__ bq,
                                           const ushort* __restrict__ Kmat,
                                           float* __restrict__ sbias, int blk) {
  int g = blk * 4 + (threadIdx.x >> 6);
  int lane = threadIdx.x & 63;
  if (g >= 512) return;
  ushort4 kv = ((const ushort4*)(Kmat + (size_t)g * 256))[lane];
  float4 bv = ((const float4*)bq)[lane];
  float p = b2f(kv.x) * bv.x + b2f(kv.y) * bv.y + b2f(kv.z) * bv.z + b2f(kv.w) * bv.w;
  for (int off = 32; off; off >>= 1) p += __shfl_xor(p, off);
  if (lane == 0) sbias[g] = p * 0.0625f;
}

__global__ void scan3_k(int* __restrict__ rowptr, const int* __restrict__ boff, int n) {
  int i = blockIdx.x * 256 + threadIdx.x;
  if (i == 0) rowptr[0] = 0;
  if (i < n) rowptr[i + 1] += boff[i >> 10];
}

// atomic-free fill: position = rowptr[d] + loc[i]
__global__ void fill_edges_k(const int* __restrict__ ei, const int* __restrict__ flag,
                             const int* __restrict__ rowptr, const int* __restrict__ loc,
                             int* __restrict__ eidx, int E) {
  int i = blockIdx.x * 256 + threadIdx.x;
  if (i >= E) return;
  const bool i64 = (*flag != 0);
  unsigned s = (unsigned)(i64 ? ei[2 * i] : ei[i]);
  unsigned d = (unsigned)(i64 ? ei[2 * E + 2 * i] : ei[E + i]);
  int lc = loc[i];
  if (d < NN && s < NN && lc >= 0) {
    unsigned p = (unsigned)(rowptr[d] + lc);
    if (p < (unsigned)E) eidx[p] = (int)s;
  }
}

// ------------------------------ aggregation ------------------------------
__global__ void agg64_k(const ushort* __restrict__ X, const int* __restrict__ rowptr,
                        const int* __restrict__ eidx, ushort* __restrict__ mean,
                        int r0, int M) {
  int nl = blockIdx.x * 4 + (threadIdx.x >> 6);
  int l = threadIdx.x & 63;
  int e4 = l >> 4;      // edge slot 0..3
  int d4 = l & 15;      // dim group (4 dims)
  if (nl >= M) return;
  int node = r0 + nl;
  int s = rowptr[node], e = rowptr[node + 1];
  float a0 = 0.f, a1 = 0.f, a2 = 0.f, a3 = 0.f;
  for (int i = s + e4; i < e; i += 4) {
    unsigned sc = (unsigned)eidx[i];
    if (sc < NN) {
      ushort4 v = ((const ushort4*)(X + (size_t)sc * 64))[d4];
      a0 += b2f(v.x); a1 += b2f(v.y); a2 += b2f(v.z); a3 += b2f(v.w);
    }
  }
  a0 += __shfl_xor(a0, 16); a0 += __shfl_xor(a0, 32);
  a1 += __shfl_xor(a1, 16); a1 += __shfl_xor(a1, 32);
  a2 += __shfl_xor(a2, 16); a2 += __shfl_xor(a2, 32);
  a3 += __shfl_xor(a3, 16); a3 += __shfl_xor(a3, 32);
  if (e4 == 0) {
    float inv = 1.f / (float)max(e - s, 1);
    ushort4 o; o.x = f2b(a0 * inv); o.y = f2b(a1 * inv); o.z = f2b(a2 * inv); o.w = f2b(a3 * inv);
    ((ushort4*)(mean + (size_t)nl * 64))[d4] = o;
  }
}

__global__ void agg256_k(const ushort* __restrict__ X, const int* __restrict__ rowptr,
                         const int* __restrict__ eidx, ushort* __restrict__ mean,
                         int r0, int M) {
  int nl = blockIdx.x * 4 + (threadIdx.x >> 6);
  int l = threadIdx.x & 63;
  int g = l >> 5;       // edge slot 0..1
  int d = l & 31;       // 8-dim group
  if (nl >= M) return;
  int node = r0 + nl;
  int s = rowptr[node], e = rowptr[node + 1];
  float a[8], c[8];
#pragma unroll
  for (int k = 0; k < 8; ++k) { a[k] = 0.f; c[k] = 0.f; }
  for (int i = s + g; i < e; i += 4) {
    unsigned s0 = (unsigned)eidx[i];
    if (s0 < NN) {
      ushort8 v = *(const ushort8*)(X + (size_t)s0 * 256 + d * 8);
#pragma unroll
      for (int k = 0; k < 8; ++k) a[k] += b2f((ushort)v[k]);
    }
    int i2 = i + 2;
    if (i2 < e) {
      unsigned s1 = (unsigned)eidx[i2];
      if (s1 < NN) {
        ushort8 v = *(const ushort8*)(X + (size_t)s1 * 256 + d * 8);
#pragma unroll
        for (int k = 0; k < 8; ++k) c[k] += b2f((ushort)v[k]);
      }
    }
  }
  float inv = 1.f / (float)max(e - s, 1);
  ushort8 o;
#pragma unroll
  for (int k = 0; k < 8; ++k) {
    float t = a[k] + c[k];
    t += __shfl_xor(t, 32);
    o[k] = (short)f2b(t * inv);
  }
  if (g == 0) *(ushort8*)(mean + (size_t)nl * 256 + d * 8) = o;
}

// ------------------------------ bf16 MFMA GEMM body (2-phase dbuf, BM=128/BK=64) ------------------------------
// used by stage2/stage3 pre-kernels only
template<int BN, bool RELU, bool OUTBF>
__device__ __forceinline__ void gemm_body(
    const ushort* __restrict__ A1, const ushort* __restrict__ BT1, int K1,
    const ushort* __restrict__ A2, const ushort* __restrict__ BT2, int K2,
    const float* __restrict__ bias, void* __restrict__ Cv, int M, int Nc,
    int bmi, int bni, char* smem) {
  constexpr int NR = BN / 32;
  constexpr int WTN = BN / 2;
  constexpr int ABYT = 128 * 64 * 2;
  constexpr int BBYT = BN * 64 * 2;
  constexpr int BUF = ABYT + BBYT;
  constexpr int CP = BN + 8;
  const int tid = threadIdx.x;
  const int l = tid & 63;
  const int w = tid >> 6;
  const int wm = w >> 1, wn = w & 1;
  const int bm = bmi * 128, bn = bni * BN;
  const int r15 = l & 15, g4 = l >> 4;

  const int nt1 = K1 >> 6;
  const int nt2 = A2 ? (K2 >> 6) : 0;
  const int nt = nt1 + nt2;

  auto STAGE = [&](int buf, int t) {
    const ushort* A = (t < nt1) ? A1 : A2;
    const ushort* BT = (t < nt1) ? BT1 : BT2;
    const int K = (t < nt1) ? K1 : K2;
    const int k0 = ((t < nt1) ? t : t - nt1) << 6;
    char* As = smem + buf * BUF;
    char* Bs = As + ABYT;
#pragma unroll
    for (int p = 0; p < 4; ++p) {
      int idx = tid + p * 256;
      int row = idx >> 3, slot = idx & 7;
      int kb = slot ^ (row & 7);
      int grow = bm + row; if (grow >= M) grow = M - 1;
      gl_lds16(A + (size_t)grow * K + k0 + kb * 8, As + idx * 16);
    }
#pragma unroll
    for (int p = 0; p < BN / 32; ++p) {
      int idx = tid + p * 256;
      int row = idx >> 3, slot = idx & 7;
      int kb = slot ^ (row & 7);
      gl_lds16(BT + (size_t)(bn + row) * K + k0 + kb * 8, Bs + idx * 16);
    }
  };

  f32x4 acc[4][NR];
  const f32x4 zz = {0.f, 0.f, 0.f, 0.f};
#pragma unroll
  for (int m = 0; m < 4; ++m)
#pragma unroll
    for (int n = 0; n < NR; ++n) acc[m][n] = zz;

  STAGE(0, 0);
  int cur = 0;
  for (int t = 0; t < nt; ++t) {
    __syncthreads();
    if (t + 1 < nt) STAGE(cur ^ 1, t + 1);
    const char* As = smem + cur * BUF;
    const char* Bs = As + ABYT;
#pragma unroll
    for (int s = 0; s < 2; ++s) {
      short8 a[4], b[NR];
      const int slotx = (((s * 4 + g4) ^ (r15 & 7)) << 4);
#pragma unroll
      for (int m = 0; m < 4; ++m) {
        int row = wm * 64 + m * 16 + r15;
        a[m] = *(const short8*)(As + row * 128 + slotx);
      }
#pragma unroll
      for (int n = 0; n < NR; ++n) {
        int row = wn * WTN + n * 16 + r15;
        b[n] = *(const short8*)(Bs + row * 128 + slotx);
      }
#pragma unroll
      for (int m = 0; m < 4; ++m)
#pragma unroll
        for (int n = 0; n < NR; ++n)
          acc[m][n] = __builtin_amdgcn_mfma_f32_16x16x32_bf16(a[m], b[n], acc[m][n], 0, 0, 0);
    }
    cur ^= 1;
  }
  __syncthreads();
  if (OUTBF) {
    ushort* Cs = (ushort*)smem;
#pragma unroll
    for (int n = 0; n < NR; ++n) {
      int col = wn * WTN + n * 16 + r15;
      float bv = bias ? bias[bn + col] : 0.f;
#pragma unroll
      for (int m = 0; m < 4; ++m) {
#pragma unroll
        for (int j = 0; j < 4; ++j) {
          int row = wm * 64 + m * 16 + g4 * 4 + j;
          float v = acc[m][n][j] + bv;
          if (RELU) v = fmaxf(v, 0.f);
          Cs[row * CP + col] = f2b(v);
        }
      }
    }
    __syncthreads();
    constexpr int C8 = BN / 8;
    for (int it = tid; it < 128 * C8; it += 256) {
      int row = it / C8, c8 = it % C8;
      if (bm + row < M)
        *(ushort8*)((ushort*)Cv + (size_t)(bm + row) * Nc + bn + c8 * 8) =
            *(const ushort8*)(Cs + row * CP + c8 * 8);
    }
  } else {
#pragma unroll
    for (int n = 0; n < NR; ++n) {
      int col = bn + wn * WTN + n * 16 + r15;
      float bv = bias ? bias[col] : 0.f;
#pragma unroll
      for (int m = 0; m < 4; ++m) {
#pragma unroll
        for (int j = 0; j < 4; ++j) {
          int row = bm + wm * 64 + m * 16 + g4 * 4 + j;
          if (row < M) {
            float v = acc[m][n][j] + bv;
            if (RELU) v = fmaxf(v, 0.f);
            ((float*)Cv)[(size_t)row * Nc + col] = v;
          }
        }
      }
    }
  }
}

// ------------------------------ bf16 MFMA GEMM (BM=128 via 8 waves, BK=32, BN=256/grid.y, dbuf) ------------------------------
// 512 threads: waves 0-3 -> rows [0,64), waves 4-7 -> rows [64,128); shared
// B stage. Per-wave code identical to R26 (acc[2][8]). Swizzle (row>>1)&3.
template<bool RELU>
__global__ __launch_bounds__(512)
void gemm64_k(const ushort* __restrict__ A1, const ushort* __restrict__ BT1, int K1,
              const ushort* __restrict__ A2, const ushort* __restrict__ BT2, int K2,
              const float* __restrict__ bias, ushort* __restrict__ C, int M, int Nc) {
  constexpr int NR = 8;              // 256 cols / 32
  constexpr int WTN = 128;           // wave col tile
  constexpr int ABYT = 128 * 32 * 2; // 8KB
  constexpr int BBYT = 256 * 32 * 2; // 16KB
  constexpr int BUF = ABYT + BBYT;   // 24KB
  constexpr int CP = 256 + 8;
  __shared__ __align__(16) char smem[2 * BUF];   // 48KB
  const int tid = threadIdx.x;
  const int l = tid & 63;
  const int w = tid >> 6;            // 0..7
  const int wh = w >> 2;             // half: rows [wh*64, wh*64+64)
  const int wm = (w >> 1) & 1, wn = w & 1;
  const int bm = blockIdx.x * 128;
  const int bn = blockIdx.y * 256;
  const int r15 = l & 15, g4 = l >> 4;

  const int nt1 = K1 >> 5;
  const int nt2 = A2 ? (K2 >> 5) : 0;
  const int nt = nt1 + nt2;

  auto STAGE = [&](int buf, int t) {
    const ushort* A = (t < nt1) ? A1 : A2;
    const ushort* BT = (t < nt1) ? BT1 : BT2;
    const int K = (t < nt1) ? K1 : K2;
    const int k0 = ((t < nt1) ? t : t - nt1) << 5;
    char* As = smem + buf * BUF;
    char* Bs = As + ABYT;
    {   // A: 128 rows x 4 slots = 512 chunks, 1/thread
      int row = tid >> 2, slot = tid & 3;
      int kb = slot ^ ((row >> 1) & 3);
      int grow = bm + row; if (grow >= M) grow = M - 1;
      gl_lds16(A + (size_t)grow * K + k0 + kb * 8, As + tid * 16);
    }
#pragma unroll
    for (int p = 0; p < 2; ++p) {   // B: 256 rows x 4 slots = 1024 chunks, 2/thread
      int idx = tid + p * 512;
      int row = idx >> 2, slot = idx & 3;
      int kb = slot ^ ((row >> 1) & 3);
      gl_lds16(BT + (size_t)(bn + row) * K + k0 + kb * 8, Bs + idx * 16);
    }
  };

  f32x4 acc[2][NR];
  const f32x4 zz = {0.f, 0.f, 0.f, 0.f};
#pragma unroll
  for (int m = 0; m < 2; ++m)
#pragma unroll
    for (int n = 0; n < NR; ++n) acc[m][n] = zz;

  STAGE(0, 0);
  int cur = 0;
  for (int t = 0; t < nt; ++t) {
    __syncthreads();
    if (t + 1 < nt) STAGE(cur ^ 1, t + 1);
    const char* As = smem + cur * BUF;
    const char* Bs = As + ABYT;
    short8 a[2], b[NR];
#pragma unroll
    for (int m = 0; m < 2; ++m) {
      int row = wh * 64 + wm * 32 + m * 16 + r15;
      a[m] = *(const short8*)(As + row * 64 + ((g4 ^ ((row >> 1) & 3)) << 4));
    }
#pragma unroll
    for (int n = 0; n < NR; ++n) {
      int row = wn * WTN + n * 16 + r15;
      b[n] = *(const short8*)(Bs + row * 64 + ((g4 ^ ((row >> 1) & 3)) << 4));
    }
#pragma unroll
    for (int m = 0; m < 2; ++m)
#pragma unroll
      for (int n = 0; n < NR; ++n)
        acc[m][n] = __builtin_amdgcn_mfma_f32_16x16x32_bf16(a[m], b[n], acc[m][n], 0, 0, 0);
    cur ^= 1;
  }
  // epilogue: LDS-staged coalesced bf16 stores, 64 rows per pass
  ushort* Cs = (ushort*)smem;
#pragma unroll
  for (int half = 0; half < 2; ++half) {
    __syncthreads();
    if (wh == half) {
#pragma unroll
      for (int n = 0; n < NR; ++n) {
        int col = wn * WTN + n * 16 + r15;
        float bv = bias ? bias[bn + col] : 0.f;
#pragma unroll
        for (int m = 0; m < 2; ++m) {
#pragma unroll
          for (int j = 0; j < 4; ++j) {
            int row = wm * 32 + m * 16 + g4 * 4 + j;
            float v = acc[m][n][j] + bv;
            if (RELU) v = fmaxf(v, 0.f);
            Cs[row * CP + col] = f2b(v);
          }
        }
      }
    }
    __syncthreads();
    for (int it = tid; it < 64 * 32; it += 512) {
      int row = it >> 5, c8 = it & 31;
      int gr = bm + half * 64 + row;
      if (gr < M)
        *(ushort8*)(C + (size_t)gr * Nc + bn + c8 * 8) =
            *(const ushort8*)(Cs + row * CP + c8 * 8);
    }
  }
}

// ------------------------------ stage2: scan1 | Kmat | Vmat | embed ------------------------------
__global__ __launch_bounds__(256)
void stage2_k(const int* __restrict__ cnt, int* __restrict__ rowptr, int* __restrict__ bsum,
              const ushort* __restrict__ gcb, const ushort* __restrict__ WkT,
              const float* __restrict__ bk, ushort* __restrict__ Kmatb,
              const ushort* __restrict__ WvT, const float* __restrict__ bvv,
              ushort* __restrict__ Vmatb,
              const ushort* __restrict__ xb, const ushort* __restrict__ WpT,
              const float* __restrict__ bp, ushort* __restrict__ x_emb) {
  __shared__ __align__(16) char smem[65536];
  int b = blockIdx.x;
  if (b < 8) {
    gemm_body<128, false, true>(gcb, WkT, 256, nullptr, nullptr, 0, bk, Kmatb,
                                512, 256, b & 3, b >> 2, smem);
  } else if (b < 16) {
    int lb = b - 8;
    gemm_body<128, false, true>(gcb, WvT, 256, nullptr, nullptr, 0, bvv, Vmatb,
                                512, 256, lb & 3, lb >> 2, smem);
  } else if (b < 16 + EMB_MB) {
    gemm_body<64, true, true>(xb, WpT, 128, nullptr, nullptr, 0, bp, x_emb,
                              NN, 64, b - 16, 0, smem);
  } else {
    scan1_body(cnt, rowptr, bsum, NN, b - (16 + EMB_MB), smem);
  }
}

// ------------------------------ stage3: scan2 | KWqT | W_pv | sbias ------------------------------
__global__ __launch_bounds__(256)
void stage3_k(const ushort* __restrict__ Kmatb, const ushort* __restrict__ Wqb,
              ushort* __restrict__ KWqT,
              const ushort* __restrict__ Wm1bT, const ushort* __restrict__ Vmatb,
              ushort* __restrict__ W_pvT,
              const float* __restrict__ bq, float* __restrict__ sbias,
              const int* __restrict__ bsum, int* __restrict__ boff) {
  __shared__ __align__(16) char smem[65536];
  int b = blockIdx.x;
  if (b < 8) {
    gemm_body<128, false, true>(Kmatb, Wqb, 256, nullptr, nullptr, 0, nullptr, KWqT,
                                512, 256, b & 3, b >> 2, smem);
  } else if (b < 16) {
    int lb = b - 8;
    gemm_body<128, false, true>(Wm1bT, Vmatb, 256, nullptr, nullptr, 0, nullptr, W_pvT,
                                256, 512, lb & 1, lb >> 1, smem);
  } else if (b < 144) {
    sbias_body(bq, Kmatb, sbias, b - 16);
  } else {
    scan2_body(bsum, boff, NB1, smem);
  }
}

// ------------------------------ fused MLP + output head (BM=128 via 8 waves, BK=32, dbuf) ------------------------------
__global__ __launch_bounds__(512)
void mlp_out_k(const ushort* __restrict__ A1, const ushort* __restrict__ BT1, int K1,
               const ushort* __restrict__ A2, const ushort* __restrict__ BT2, int K2,
               const float* __restrict__ bias, const float* __restrict__ Wm2,
               const float* __restrict__ bm2, float* __restrict__ out, int M) {
  constexpr int NR = 8;              // 256 cols / 32
  constexpr int WTN = 128;           // wave col tile
  constexpr int ABYT = 128 * 32 * 2; // 8KB
  constexpr int BBYT = 256 * 32 * 2; // 16KB
  constexpr int BUF = ABYT + BBYT;   // 24KB
  __shared__ __align__(16) char smem[2 * BUF];   // 48KB
  const int tid = threadIdx.x;
  const int l = tid & 63;
  const int w = tid >> 6;            // 0..7
  const int wh = w >> 2;
  const int wm = (w >> 1) & 1, wn = w & 1;
  const int bm = blockIdx.x * 128;
  const int r15 = l & 15, g4 = l >> 4;

  const int nt1 = K1 >> 5;
  const int nt2 = K2 >> 5;
  const int nt = nt1 + nt2;

  auto STAGE = [&](int buf, int t) {
    const ushort* A = (t < nt1) ? A1 : A2;
    const ushort* BT = (t < nt1) ? BT1 : BT2;
    const int K = (t < nt1) ? K1 : K2;
    const int k0 = ((t < nt1) ? t : t - nt1) << 5;
    char* As = smem + buf * BUF;
    char* Bs = As + ABYT;
    {   // A: 128 rows x 4 slots = 512 chunks, 1/thread
      int row = tid >> 2, slot = tid & 3;
      int kb = slot ^ ((row >> 1) & 3);
      int grow = bm + row; if (grow >= M) grow = M - 1;
      gl_lds16(A + (size_t)grow * K + k0 + kb * 8, As + tid * 16);
    }
#pragma unroll
    for (int p = 0; p < 2; ++p) {   // B: 256 rows x 4 slots = 1024 chunks, 2/thread
      int idx = tid + p * 512;
      int row = idx >> 2, slot = idx & 3;
      int kb = slot ^ ((row >> 1) & 3);
      gl_lds16(BT + (size_t)row * K + k0 + kb * 8, Bs + idx * 16);
    }
  };

  f32x4 acc[2][NR];
  const f32x4 zz = {0.f, 0.f, 0.f, 0.f};
#pragma unroll
  for (int m = 0; m < 2; ++m)
#pragma unroll
    for (int n = 0; n < NR; ++n) acc[m][n] = zz;

  STAGE(0, 0);
  int cur = 0;
  for (int t = 0; t < nt; ++t) {
    __syncthreads();
    if (t + 1 < nt) STAGE(cur ^ 1, t + 1);
    const char* As = smem + cur * BUF;
    const char* Bs = As + ABYT;
    short8 a[2], b[NR];
#pragma unroll
    for (int m = 0; m < 2; ++m) {
      int row = wh * 64 + wm * 32 + m * 16 + r15;
      a[m] = *(const short8*)(As + row * 64 + ((g4 ^ ((row >> 1) & 3)) << 4));
    }
#pragma unroll
    for (int n = 0; n < NR; ++n) {
      int row = wn * WTN + n * 16 + r15;
      b[n] = *(const short8*)(Bs + row * 64 + ((g4 ^ ((row >> 1) & 3)) << 4));
    }
#pragma unroll
    for (int m = 0; m < 2; ++m)
#pragma unroll
      for (int n = 0; n < NR; ++n)
        acc[m][n] = __builtin_amdgcn_mfma_f32_16x16x32_bf16(a[m], b[n], acc[m][n], 0, 0, 0);
    cur ^= 1;
  }
  __syncthreads();
  float bv[NR], w20[NR], w21[NR];
#pragma unroll
  for (int n = 0; n < NR; ++n) {
    int col = wn * WTN + n * 16 + r15;
    bv[n] = bias[col];
    w20[n] = Wm2[col * 2 + 0];
    w21[n] = Wm2[col * 2 + 1];
  }
  float* red = (float*)smem;   // 2KB
#pragma unroll
  for (int m = 0; m < 2; ++m) {
#pragma unroll
    for (int j = 0; j < 4; ++j) {
      float p0 = 0.f, p1 = 0.f;
#pragma unroll
      for (int n = 0; n < NR; ++n) {
        float v = fmaxf(acc[m][n][j] + bv[n], 0.f);
        p0 += v * w20[n];
        p1 += v * w21[n];
      }
      p0 += __shfl_xor(p0, 1); p1 += __shfl_xor(p1, 1);
      p0 += __shfl_xor(p0, 2); p1 += __shfl_xor(p1, 2);
      p0 += __shfl_xor(p0, 4); p1 += __shfl_xor(p1, 4);
      p0 += __shfl_xor(p0, 8); p1 += __shfl_xor(p1, 8);
      if (r15 == 0) {
        int rl = wh * 64 + wm * 32 + m * 16 + g4 * 4 + j;
        red[wn * 256 + rl * 2 + 0] = p0;
        red[wn * 256 + rl * 2 + 1] = p1;
      }
    }
  }
  __syncthreads();
  if (tid < 256) {
    int rl = tid >> 1, j = tid & 1;   // 128 rows x 2 outputs
    int row = bm + rl;
    if (row < M)
      out[(size_t)row * 2 + j] = red[rl * 2 + j] + red[256 + rl * 2 + j] + bm2[j];
  }
}

// ------------------------------ softmax in place (pre-scaled bf16 logits -> bf16 P) ------------------------------
__global__ void softmax_k(ushort* __restrict__ SP, int M) {
  int row = blockIdx.x * 4 + (threadIdx.x >> 6);
  int lane = threadIdx.x & 63;
  if (row >= M) return;
  ushort4* p = (ushort4*)(SP + (size_t)row * 512);
  ushort4 ua = p[lane];
  ushort4 ub = p[lane + 64];
  float ax = b2f(ua.x), ay = b2f(ua.y), az = b2f(ua.z), aw = b2f(ua.w);
  float bx = b2f(ub.x), by = b2f(ub.y), bz = b2f(ub.z), bw = b2f(ub.w);
  float m = fmaxf(fmaxf(fmaxf(ax, ay), fmaxf(az, aw)),
                  fmaxf(fmaxf(bx, by), fmaxf(bz, bw)));
  for (int off = 32; off; off >>= 1) m = fmaxf(m, __shfl_xor(m, off));
  ax = expf(ax - m); ay = expf(ay - m); az = expf(az - m); aw = expf(aw - m);
  bx = expf(bx - m); by = expf(by - m); bz = expf(bz - m); bw = expf(bw - m);
  float s = ax + ay + az + aw + bx + by + bz + bw;
  for (int off = 32; off; off >>= 1) s += __shfl_xor(s, off);
  float inv = 1.f / s;
  ushort4 oa, ob;
  oa.x = f2b(ax * inv); oa.y = f2b(ay * inv); oa.z = f2b(az * inv); oa.w = f2b(aw * inv);
  ob.x = f2b(bx * inv); ob.y = f2b(by * inv); ob.z = f2b(bz * inv); ob.w = f2b(bw * inv);
  p[lane] = oa;
  p[lane + 64] = ob;
}

// ------------------------------ launch ------------------------------
extern "C" void kernel_launch(void* const* d_in, const int* in_sizes, int n_in,
                              void* d_out, int out_size, void* d_ws, size_t ws_size,
                              hipStream_t stream) {
  const int N = NN, E = NE;
  const float* x   = (const float*)d_in[0];
  const int*   ei  = (const int*)d_in[1];
  const float* gc  = (const float*)d_in[2];
  const float* Wp  = (const float*)d_in[3];
  const float* bp  = (const float*)d_in[4];
  const float* W1l = (const float*)d_in[5];
  const float* b1l = (const float*)d_in[6];
  const float* W1r = (const float*)d_in[7];
  const float* W2l = (const float*)d_in[8];
  const float* b2l = (const float*)d_in[9];
  const float* W2r = (const float*)d_in[10];
  const float* Wq  = (const float*)d_in[11];
  const float* bq  = (const float*)d_in[12];
  const float* Wk  = (const float*)d_in[13];
  const float* bk  = (const float*)d_in[14];
  const float* Wv  = (const float*)d_in[15];
  const float* bv  = (const float*)d_in[16];
  const float* Wm1 = (const float*)d_in[17];
  const float* bm1 = (const float*)d_in[18];
  const float* Wm2 = (const float*)d_in[19];
  const float* bm2 = (const float*)d_in[20];
  float* out = (float*)d_out;

  char* base = (char*)d_ws;
  size_t off = 0;
  auto take = [&](size_t bytes) -> void* {
    void* r = base + off;
    off += (bytes + 255) & ~(size_t)255;
    return r;
  };
  // CSR + misc
  int* cnt    = (int*)take((size_t)N * 4);
  int* rowptr = (int*)take((size_t)(N + 1) * 4);
  int* loc    = (int*)take((size_t)E * 4);
  int* eidx   = (int*)take((size_t)E * 4);
  int* eflag  = (int*)take(256);
  int* bsum   = (int*)take(NB1 * 4);
  int* boff   = (int*)take(NB1 * 4);
  // bf16 weights
  ushort* WpT   = (ushort*)take((size_t)64 * 128 * 2);
  ushort* W1lT  = (ushort*)take((size_t)256 * 64 * 2);
  ushort* W1rT  = (ushort*)take((size_t)256 * 64 * 2);
  ushort* W2lT  = (ushort*)take((size_t)256 * 256 * 2);
  ushort* W2rT  = (ushort*)take((size_t)256 * 256 * 2);
  ushort* WkT   = (ushort*)take((size_t)256 * 256 * 2);
  ushort* WvT   = (ushort*)take((size_t)256 * 256 * 2);
  ushort* Wqb   = (ushort*)take((size_t)256 * 256 * 2);
  ushort* Wm1aT = (ushort*)take((size_t)256 * 256 * 2);
  ushort* Wm1bT = (ushort*)take((size_t)256 * 256 * 2);
  // attention small
  ushort* gcb   = (ushort*)take((size_t)512 * 256 * 2);
  ushort* Kmatb = (ushort*)take((size_t)512 * 256 * 2);
  ushort* Vmatb = (ushort*)take((size_t)512 * 256 * 2);
  ushort* W_pvT = (ushort*)take((size_t)256 * 512 * 2);
  ushort* KWqT  = (ushort*)take((size_t)512 * 256 * 2);
  float*  sbias = (float*)take((size_t)512 * 4);
  // region U (full-size, single chunk): h2 [N*512B] + SP [N*1024B]; mean2
  // aliases SP lower half (dead before S written); pre-loop xb/x_emb/mean1
  // (N*512B total) fit in the h2 segment + start of SP.
  char* U = (char*)take((size_t)N * 1536);
  ushort* h = (ushort*)take((size_t)N * 256 * 2);   // live whole run
  if (off > ws_size) return;

  ushort* xb    = (ushort*)U;                           // N*256B (pre-loop)
  ushort* x_emb = (ushort*)(U + (size_t)N * 256);       // N*128B (pre-loop)
  ushort* mean1 = (ushort*)(U + (size_t)N * 384);       // N*128B (pre-loop)
  ushort* h2_c     = (ushort*)U;                        // N*512B
  ushort* SP_c     = (ushort*)(U + (size_t)N * 512);    // N*1024B (S then P)
  ushort* mean2_c  = SP_c;                              // aliases SP lower half

  const int n4 = N * 128 / 4;
  dim3 thr(256);
  dim3 thr512(512);

  // CvtJobs (Wqb pre-scaled by 1/16 to fold softmax scale)
  CvtJobs jb;
  {
    const float* s_[NJOB] = {gc, Wq, Wp, W1l, W1r, W2l, W2r, Wk, Wv, Wm1, Wm1};
    ushort* d_[NJOB] = {gcb, Wqb, WpT, W1lT, W1rT, W2lT, W2rT, WkT, WvT, Wm1aT, Wm1bT};
    int R_[NJOB] = {512, 256, 128, 64, 64, 256, 256, 256, 256, 256, 256};
    int C_[NJOB] = {256, 256, 64, 256, 256, 256, 256, 256, 256, 256, 256};
    int o_[NJOB] = {0, 0, 0, 0, 0, 0, 0, 0, 0, 0, 256};
    int t_[NJOB] = {0, 0, 1, 1, 1, 1, 1, 1, 1, 1, 1};
    for (int j = 0; j < NJOB; ++j) {
      jb.src[j] = s_[j]; jb.dst[j] = d_[j]; jb.R[j] = R_[j]; jb.C[j] = C_[j];
      jb.off[j] = o_[j]; jb.tr[j] = t_[j]; jb.sc[j] = (j == 1) ? 0.0625f : 1.0f;
    }
  }

  // CSR build + all conversions (count/x-cvt interleaved 1:4, w-cvt tail)
  zero_detect_k<<<1 + (N + 255) / 256, thr, 0, stream>>>(ei, eflag, cnt, N);
  count_cvt_k<<<CNTB + XCVB + WCVB, thr, 0, stream>>>(ei, eflag, cnt, loc, x, xb, E, n4, jb);
  // stage2: scan1 | Kmat | Vmat | embed (all depend only on count_cvt)
  stage2_k<<<16 + EMB_MB + NB1, thr, 0, stream>>>(
      cnt, rowptr, bsum, gcb, WkT, bk, Kmatb, WvT, bv, Vmatb, xb, WpT, bp, x_emb);
  // stage3: scan2 | KWqT | W_pv | sbias (all depend only on stage2)
  stage3_k<<<145, thr, 0, stream>>>(
      Kmatb, Wqb, KWqT, Wm1bT, Vmatb, W_pvT, bq, sbias, bsum, boff);
  scan3_k<<<(N + 255) / 256, thr, 0, stream>>>(rowptr, boff, N);
  fill_edges_k<<<(E + 255) / 256, thr, 0, stream>>>(ei, eflag, rowptr, loc, eidx, E);

  // SAGE1 (8-wave BM=128/BK=32 shape)
  agg64_k<<<(N + 3) / 4, thr, 0, stream>>>(x_emb, rowptr, eidx, mean1, 0, N);
  gemm64_k<true><<<dim3((N + 127) / 128, 1), thr512, 0, stream>>>(
      mean1, W1lT, 64, x_emb, W1rT, 64, b1l, h, N, 256);

  // single-pass SAGE2 + attention + fused MLP/out (PV folded via W_pv)
  {
    const int CRc = N;
    const int MBc128 = (CRc + 127) / 128;
    agg256_k<<<(CRc + 3) / 4, thr, 0, stream>>>(h, rowptr, eidx, mean2_c, 0, CRc);
    gemm64_k<false><<<dim3(MBc128, 1), thr512, 0, stream>>>(
        mean2_c, W2lT, 256, h, W2rT, 256, b2l, h2_c, CRc, 256);
    gemm64_k<false><<<dim3(MBc128, 2), thr512, 0, stream>>>(
        h2_c, KWqT, 256, nullptr, nullptr, 0, sbias, SP_c, CRc, 512);
    softmax_k<<<(CRc + 3) / 4, thr, 0, stream>>>(SP_c, CRc);
    mlp_out_k<<<dim3(MBc128, 1), thr512, 0, stream>>>(
        h2_c, Wm1aT, 256, SP_c, W_pvT, 512, bm1, Wm2, bm2, out, CRc);
  }
}

// Round 29
// 398.349 us; speedup vs baseline: 1.3250x; 1.0120x over previous
//
#include <hip/hip_runtime.h>
#include <cstdint>
#include <cstddef>

// GAAPModelB on MI355X: bf16-MFMA GEMM stack + CSR gather aggregation.
// N=100000, E=800000, IN=128, H=256, G=512.
// R29 (= R28 + agg256 4-deep load pipeline). agg256 was top-1 (69us,
// 44% BW / 42% VALU, 2 loads in flight). Now 4 slot loads issued before
// accumulation; accumulation order preserved (a: i,i+4,...; c: i+2,i+6,...)
// -> bit-identical to R28.

#define NN 100000
#define NE 800000
#define CR 100000  // single chunk
#define NB1 98     // ceil(100000/1024) scan blocks
#define CNTB 3125  // count-role blocks (1 in 5 of first 15625)
#define XCVB 12500 // x-cvt-role blocks
#define NJOB 11
#define WCVB (NJOB * 32)
#define EMB_MB 782 // ceil(100000/128)

typedef __attribute__((ext_vector_type(8))) short short8;
typedef __attribute__((ext_vector_type(8))) unsigned short ushort8;
typedef __attribute__((ext_vector_type(4))) float f32x4;

__device__ __forceinline__ float b2f(ushort u) {
  union { unsigned u; float f; } v; v.u = ((unsigned)u) << 16; return v.f;
}
__device__ __forceinline__ ushort f2b(float f) {
  union { float f; unsigned u; } v; v.f = f;
  unsigned r = v.u + 0x7FFFu + ((v.u >> 16) & 1u);
  return (ushort)(r >> 16);
}
__device__ __forceinline__ void gl_lds16(const void* g, void* l) {
  __builtin_amdgcn_global_load_lds((const __attribute__((address_space(1))) void*)g,
                                   (__attribute__((address_space(3))) void*)l, 16, 0, 0);
}

// ------------------------------ utility ------------------------------
// block 0: detect int64 edge layout; blocks 1..: zero cnt
__global__ void zero_detect_k(const int* __restrict__ ei, int* __restrict__ flag,
                              int* __restrict__ cnt, int n) {
  if (blockIdx.x == 0) {
    __shared__ int ok;
    int t = threadIdx.x;
    if (t == 0) ok = 1;
    __syncthreads();
    if (ei[2 * t + 1] != 0) ok = 0;
    __syncthreads();
    if (t == 0) *flag = ok;
  } else {
    int i = (blockIdx.x - 1) * 256 + threadIdx.x;
    if (i < n) cnt[i] = 0;
  }
}

struct CvtJobs {
  const float* src[NJOB];
  ushort* dst[NJOB];
  int R[NJOB], C[NJOB], off[NJOB], tr[NJOB];
  float sc[NJOB];
};

// ------------------------------ CSR build + conversions (3 roles, interleaved) ------------------------------
__global__ void count_cvt_k(const int* __restrict__ ei, const int* __restrict__ flag,
                            int* __restrict__ cnt, int* __restrict__ loc,
                            const float* __restrict__ x, ushort* __restrict__ xb,
                            int E, int n4, CvtJobs jb) {
  int b = blockIdx.x;
  if (b < CNTB + XCVB) {
    int q = b / 5;
    if (b - q * 5 == 0) {
      int i = q * 256 + threadIdx.x;
      if (i >= E) return;
      const bool i64 = (*flag != 0);
      unsigned d = (unsigned)(i64 ? ei[2 * E + 2 * i] : ei[E + i]);
      int p = -1;
      if (d < NN) p = atomicAdd(&cnt[d], 1);
      loc[i] = p;
    } else {
      int i = (b - q - 1) * 256 + threadIdx.x;
      if (i < n4) {
        float4 v = ((const float4*)x)[i];
        ushort4 o; o.x = f2b(v.x); o.y = f2b(v.y); o.z = f2b(v.z); o.w = f2b(v.w);
        ((ushort4*)xb)[i] = o;
      }
    }
  } else {
    int wb = b - CNTB - XCVB;
    int j = wb >> 5;            // job
    int ib = wb & 31;           // inner block
    const int Cj = jb.C[j], Rj = jb.R[j];
    const float sc = jb.sc[j];
    const int n = Rj * Cj;
    if (jb.tr[j]) {
      for (int i = ib * 256 + threadIdx.x; i < n; i += 32 * 256) {
        int c = i / Rj, r = i - c * Rj;
        jb.dst[j][i] = f2b(jb.src[j][(size_t)(jb.off[j] + r) * Cj + c] * sc);
      }
    } else {
      for (int i = ib * 256 + threadIdx.x; i < n; i += 32 * 256)
        jb.dst[j][i] = f2b(jb.src[j][i] * sc);
    }
  }
}

// ------------------------------ scan bodies ------------------------------
__device__ __forceinline__ void scan1_body(const int* __restrict__ cnt,
                                           int* __restrict__ rowptr,
                                           int* __restrict__ bsum, int n, int b,
                                           char* smem) {
  int* ls = (int*)smem;
  const int t = threadIdx.x;
  const int base = b * 1024 + t * 4;
  int v[4]; int s = 0;
#pragma unroll
  for (int j = 0; j < 4; ++j) { int i = base + j; v[j] = (i < n) ? cnt[i] : 0; s += v[j]; }
  ls[t] = s; __syncthreads();
  int x = s;
  for (int o = 1; o < 256; o <<= 1) {
    int a = (t >= o) ? ls[t - o] : 0; __syncthreads();
    x += a; ls[t] = x; __syncthreads();
  }
  int run = x - s;
#pragma unroll
  for (int j = 0; j < 4; ++j) { run += v[j]; int i = base + j; if (i < n) rowptr[i + 1] = run; }
  if (t == 255) bsum[b] = x;
}

__device__ __forceinline__ void scan2_body(const int* __restrict__ bsum,
                                           int* __restrict__ boff, int nb,
                                           char* smem) {
  int* ls = (int*)smem;
  int t = threadIdx.x;
  int v = (t < 128 && t < nb) ? bsum[t] : 0;
  if (t < 128) ls[t] = v;
  __syncthreads();
  int x = v;
  for (int o = 1; o < 128; o <<= 1) {
    int a = (t < 128 && t >= o) ? ls[t - o] : 0;
    __syncthreads();
    x += a;
    if (t < 128) ls[t] = x;
    __syncthreads();
  }
  if (t < 128 && t < nb) boff[t] = x - v;
}

__device__ __forceinline__ void sbias_body(const float* __restrict__ bq,
                                           const ushort* __restrict__ Kmat,
                                           float* __restrict__ sbias, int blk) {
  int g = blk * 4 + (threadIdx.x >> 6);
  int lane = threadIdx.x & 63;
  if (g >= 512) return;
  ushort4 kv = ((const ushort4*)(Kmat + (size_t)g * 256))[lane];
  float4 bv = ((const float4*)bq)[lane];
  float p = b2f(kv.x) * bv.x + b2f(kv.y) * bv.y + b2f(kv.z) * bv.z + b2f(kv.w) * bv.w;
  for (int off = 32; off; off >>= 1) p += __shfl_xor(p, off);
  if (lane == 0) sbias[g] = p * 0.0625f;
}

__global__ void scan3_k(int* __restrict__ rowptr, const int* __restrict__ boff, int n) {
  int i = blockIdx.x * 256 + threadIdx.x;
  if (i == 0) rowptr[0] = 0;
  if (i < n) rowptr[i + 1] += boff[i >> 10];
}

// atomic-free fill: position = rowptr[d] + loc[i]
__global__ void fill_edges_k(const int* __restrict__ ei, const int* __restrict__ flag,
                             const int* __restrict__ rowptr, const int* __restrict__ loc,
                             int* __restrict__ eidx, int E) {
  int i = blockIdx.x * 256 + threadIdx.x;
  if (i >= E) return;
  const bool i64 = (*flag != 0);
  unsigned s = (unsigned)(i64 ? ei[2 * i] : ei[i]);
  unsigned d = (unsigned)(i64 ? ei[2 * E + 2 * i] : ei[E + i]);
  int lc = loc[i];
  if (d < NN && s < NN && lc >= 0) {
    unsigned p = (unsigned)(rowptr[d] + lc);
    if (p < (unsigned)E) eidx[p] = (int)s;
  }
}

// ------------------------------ aggregation ------------------------------
__global__ void agg64_k(const ushort* __restrict__ X, const int* __restrict__ rowptr,
                        const int* __restrict__ eidx, ushort* __restrict__ mean,
                        int r0, int M) {
  int nl = blockIdx.x * 4 + (threadIdx.x >> 6);
  int l = threadIdx.x & 63;
  int e4 = l >> 4;      // edge slot 0..3
  int d4 = l & 15;      // dim group (4 dims)
  if (nl >= M) return;
  int node = r0 + nl;
  int s = rowptr[node], e = rowptr[node + 1];
  float a0 = 0.f, a1 = 0.f, a2 = 0.f, a3 = 0.f;
  for (int i = s + e4; i < e; i += 4) {
    unsigned sc = (unsigned)eidx[i];
    if (sc < NN) {
      ushort4 v = ((const ushort4*)(X + (size_t)sc * 64))[d4];
      a0 += b2f(v.x); a1 += b2f(v.y); a2 += b2f(v.z); a3 += b2f(v.w);
    }
  }
  a0 += __shfl_xor(a0, 16); a0 += __shfl_xor(a0, 32);
  a1 += __shfl_xor(a1, 16); a1 += __shfl_xor(a1, 32);
  a2 += __shfl_xor(a2, 16); a2 += __shfl_xor(a2, 32);
  a3 += __shfl_xor(a3, 16); a3 += __shfl_xor(a3, 32);
  if (e4 == 0) {
    float inv = 1.f / (float)max(e - s, 1);
    ushort4 o; o.x = f2b(a0 * inv); o.y = f2b(a1 * inv); o.z = f2b(a2 * inv); o.w = f2b(a3 * inv);
    ((ushort4*)(mean + (size_t)nl * 64))[d4] = o;
  }
}

// R29: 4 gather loads in flight per lane; accumulation ORDER preserved vs
// R28 (a: i, i+4, ...; c: i+2, i+6, ...) -> bit-identical output.
__global__ void agg256_k(const ushort* __restrict__ X, const int* __restrict__ rowptr,
                         const int* __restrict__ eidx, ushort* __restrict__ mean,
                         int r0, int M) {
  int nl = blockIdx.x * 4 + (threadIdx.x >> 6);
  int l = threadIdx.x & 63;
  int g = l >> 5;       // edge slot parity 0..1
  int d = l & 31;       // 8-dim group
  if (nl >= M) return;
  int node = r0 + nl;
  int s = rowptr[node], e = rowptr[node + 1];
  float a[8], c[8];
#pragma unroll
  for (int k = 0; k < 8; ++k) { a[k] = 0.f; c[k] = 0.f; }
  for (int i = s + g; i < e; i += 8) {
    // clamp tail indices to a valid slot (predicated accumulation below)
    int j1 = (i + 2 < e) ? i + 2 : i;
    int j2 = (i + 4 < e) ? i + 4 : i;
    int j3 = (i + 6 < e) ? i + 6 : i;
    unsigned id0 = (unsigned)eidx[i];
    unsigned id1 = (unsigned)eidx[j1];
    unsigned id2 = (unsigned)eidx[j2];
    unsigned id3 = (unsigned)eidx[j3];
    ushort8 v0 = *(const ushort8*)(X + (size_t)(id0 < NN ? id0 : 0u) * 256 + d * 8);
    ushort8 v1 = *(const ushort8*)(X + (size_t)(id1 < NN ? id1 : 0u) * 256 + d * 8);
    ushort8 v2 = *(const ushort8*)(X + (size_t)(id2 < NN ? id2 : 0u) * 256 + d * 8);
    ushort8 v3 = *(const ushort8*)(X + (size_t)(id3 < NN ? id3 : 0u) * 256 + d * 8);
    if (id0 < NN) {
#pragma unroll
      for (int k = 0; k < 8; ++k) a[k] += b2f((ushort)v0[k]);
    }
    if (i + 2 < e && id1 < NN) {
#pragma unroll
      for (int k = 0; k < 8; ++k) c[k] += b2f((ushort)v1[k]);
    }
    if (i + 4 < e && id2 < NN) {
#pragma unroll
      for (int k = 0; k < 8; ++k) a[k] += b2f((ushort)v2[k]);
    }
    if (i + 6 < e && id3 < NN) {
#pragma unroll
      for (int k = 0; k < 8; ++k) c[k] += b2f((ushort)v3[k]);
    }
  }
  float inv = 1.f / (float)max(e - s, 1);
  ushort8 o;
#pragma unroll
  for (int k = 0; k < 8; ++k) {
    float t = a[k] + c[k];
    t += __shfl_xor(t, 32);
    o[k] = (short)f2b(t * inv);
  }
  if (g == 0) *(ushort8*)(mean + (size_t)nl * 256 + d * 8) = o;
}

// ------------------------------ bf16 MFMA GEMM body (2-phase dbuf, BM=128/BK=64) ------------------------------
// used by stage2/stage3 pre-kernels only
template<int BN, bool RELU, bool OUTBF>
__device__ __forceinline__ void gemm_body(
    const ushort* __restrict__ A1, const ushort* __restrict__ BT1, int K1,
    const ushort* __restrict__ A2, const ushort* __restrict__ BT2, int K2,
    const float* __restrict__ bias, void* __restrict__ Cv, int M, int Nc,
    int bmi, int bni, char* smem) {
  constexpr int NR = BN / 32;
  constexpr int WTN = BN / 2;
  constexpr int ABYT = 128 * 64 * 2;
  constexpr int BBYT = BN * 64 * 2;
  constexpr int BUF = ABYT + BBYT;
  constexpr int CP = BN + 8;
  const int tid = threadIdx.x;
  const int l = tid & 63;
  const int w = tid >> 6;
  const int wm = w >> 1, wn = w & 1;
  const int bm = bmi * 128, bn = bni * BN;
  const int r15 = l & 15, g4 = l >> 4;

  const int nt1 = K1 >> 6;
  const int nt2 = A2 ? (K2 >> 6) : 0;
  const int nt = nt1 + nt2;

  auto STAGE = [&](int buf, int t) {
    const ushort* A = (t < nt1) ? A1 : A2;
    const ushort* BT = (t < nt1) ? BT1 : BT2;
    const int K = (t < nt1) ? K1 : K2;
    const int k0 = ((t < nt1) ? t : t - nt1) << 6;
    char* As = smem + buf * BUF;
    char* Bs = As + ABYT;
#pragma unroll
    for (int p = 0; p < 4; ++p) {
      int idx = tid + p * 256;
      int row = idx >> 3, slot = idx & 7;
      int kb = slot ^ (row & 7);
      int grow = bm + row; if (grow >= M) grow = M - 1;
      gl_lds16(A + (size_t)grow * K + k0 + kb * 8, As + idx * 16);
    }
#pragma unroll
    for (int p = 0; p < BN / 32; ++p) {
      int idx = tid + p * 256;
      int row = idx >> 3, slot = idx & 7;
      int kb = slot ^ (row & 7);
      gl_lds16(BT + (size_t)(bn + row) * K + k0 + kb * 8, Bs + idx * 16);
    }
  };

  f32x4 acc[4][NR];
  const f32x4 zz = {0.f, 0.f, 0.f, 0.f};
#pragma unroll
  for (int m = 0; m < 4; ++m)
#pragma unroll
    for (int n = 0; n < NR; ++n) acc[m][n] = zz;

  STAGE(0, 0);
  int cur = 0;
  for (int t = 0; t < nt; ++t) {
    __syncthreads();
    if (t + 1 < nt) STAGE(cur ^ 1, t + 1);
    const char* As = smem + cur * BUF;
    const char* Bs = As + ABYT;
#pragma unroll
    for (int s = 0; s < 2; ++s) {
      short8 a[4], b[NR];
      const int slotx = (((s * 4 + g4) ^ (r15 & 7)) << 4);
#pragma unroll
      for (int m = 0; m < 4; ++m) {
        int row = wm * 64 + m * 16 + r15;
        a[m] = *(const short8*)(As + row * 128 + slotx);
      }
#pragma unroll
      for (int n = 0; n < NR; ++n) {
        int row = wn * WTN + n * 16 + r15;
        b[n] = *(const short8*)(Bs + row * 128 + slotx);
      }
#pragma unroll
      for (int m = 0; m < 4; ++m)
#pragma unroll
        for (int n = 0; n < NR; ++n)
          acc[m][n] = __builtin_amdgcn_mfma_f32_16x16x32_bf16(a[m], b[n], acc[m][n], 0, 0, 0);
    }
    cur ^= 1;
  }
  __syncthreads();
  if (OUTBF) {
    ushort* Cs = (ushort*)smem;
#pragma unroll
    for (int n = 0; n < NR; ++n) {
      int col = wn * WTN + n * 16 + r15;
      float bv = bias ? bias[bn + col] : 0.f;
#pragma unroll
      for (int m = 0; m < 4; ++m) {
#pragma unroll
        for (int j = 0; j < 4; ++j) {
          int row = wm * 64 + m * 16 + g4 * 4 + j;
          float v = acc[m][n][j] + bv;
          if (RELU) v = fmaxf(v, 0.f);
          Cs[row * CP + col] = f2b(v);
        }
      }
    }
    __syncthreads();
    constexpr int C8 = BN / 8;
    for (int it = tid; it < 128 * C8; it += 256) {
      int row = it / C8, c8 = it % C8;
      if (bm + row < M)
        *(ushort8*)((ushort*)Cv + (size_t)(bm + row) * Nc + bn + c8 * 8) =
            *(const ushort8*)(Cs + row * CP + c8 * 8);
    }
  } else {
#pragma unroll
    for (int n = 0; n < NR; ++n) {
      int col = bn + wn * WTN + n * 16 + r15;
      float bv = bias ? bias[col] : 0.f;
#pragma unroll
      for (int m = 0; m < 4; ++m) {
#pragma unroll
        for (int j = 0; j < 4; ++j) {
          int row = bm + wm * 64 + m * 16 + g4 * 4 + j;
          if (row < M) {
            float v = acc[m][n][j] + bv;
            if (RELU) v = fmaxf(v, 0.f);
            ((float*)Cv)[(size_t)row * Nc + col] = v;
          }
        }
      }
    }
  }
}

// ------------------------------ bf16 MFMA GEMM (BM=128 via 8 waves, BK=32, BN=256/grid.y, dbuf) ------------------------------
// 512 threads: waves 0-3 -> rows [0,64), waves 4-7 -> rows [64,128); shared
// B stage. Per-wave code identical to R26 (acc[2][8]). Swizzle (row>>1)&3.
template<bool RELU>
__global__ __launch_bounds__(512)
void gemm64_k(const ushort* __restrict__ A1, const ushort* __restrict__ BT1, int K1,
              const ushort* __restrict__ A2, const ushort* __restrict__ BT2, int K2,
              const float* __restrict__ bias, ushort* __restrict__ C, int M, int Nc) {
  constexpr int NR = 8;              // 256 cols / 32
  constexpr int WTN = 128;           // wave col tile
  constexpr int ABYT = 128 * 32 * 2; // 8KB
  constexpr int BBYT = 256 * 32 * 2; // 16KB
  constexpr int BUF = ABYT + BBYT;   // 24KB
  constexpr int CP = 256 + 8;
  __shared__ __align__(16) char smem[2 * BUF];   // 48KB
  const int tid = threadIdx.x;
  const int l = tid & 63;
  const int w = tid >> 6;            // 0..7
  const int wh = w >> 2;             // half: rows [wh*64, wh*64+64)
  const int wm = (w >> 1) & 1, wn = w & 1;
  const int bm = blockIdx.x * 128;
  const int bn = blockIdx.y * 256;
  const int r15 = l & 15, g4 = l >> 4;

  const int nt1 = K1 >> 5;
  const int nt2 = A2 ? (K2 >> 5) : 0;
  const int nt = nt1 + nt2;

  auto STAGE = [&](int buf, int t) {
    const ushort* A = (t < nt1) ? A1 : A2;
    const ushort* BT = (t < nt1) ? BT1 : BT2;
    const int K = (t < nt1) ? K1 : K2;
    const int k0 = ((t < nt1) ? t : t - nt1) << 5;
    char* As = smem + buf * BUF;
    char* Bs = As + ABYT;
    {   // A: 128 rows x 4 slots = 512 chunks, 1/thread
      int row = tid >> 2, slot = tid & 3;
      int kb = slot ^ ((row >> 1) & 3);
      int grow = bm + row; if (grow >= M) grow = M - 1;
      gl_lds16(A + (size_t)grow * K + k0 + kb * 8, As + tid * 16);
    }
#pragma unroll
    for (int p = 0; p < 2; ++p) {   // B: 256 rows x 4 slots = 1024 chunks, 2/thread
      int idx = tid + p * 512;
      int row = idx >> 2, slot = idx & 3;
      int kb = slot ^ ((row >> 1) & 3);
      gl_lds16(BT + (size_t)(bn + row) * K + k0 + kb * 8, Bs + idx * 16);
    }
  };

  f32x4 acc[2][NR];
  const f32x4 zz = {0.f, 0.f, 0.f, 0.f};
#pragma unroll
  for (int m = 0; m < 2; ++m)
#pragma unroll
    for (int n = 0; n < NR; ++n) acc[m][n] = zz;

  STAGE(0, 0);
  int cur = 0;
  for (int t = 0; t < nt; ++t) {
    __syncthreads();
    if (t + 1 < nt) STAGE(cur ^ 1, t + 1);
    const char* As = smem + cur * BUF;
    const char* Bs = As + ABYT;
    short8 a[2], b[NR];
#pragma unroll
    for (int m = 0; m < 2; ++m) {
      int row = wh * 64 + wm * 32 + m * 16 + r15;
      a[m] = *(const short8*)(As + row * 64 + ((g4 ^ ((row >> 1) & 3)) << 4));
    }
#pragma unroll
    for (int n = 0; n < NR; ++n) {
      int row = wn * WTN + n * 16 + r15;
      b[n] = *(const short8*)(Bs + row * 64 + ((g4 ^ ((row >> 1) & 3)) << 4));
    }
#pragma unroll
    for (int m = 0; m < 2; ++m)
#pragma unroll
      for (int n = 0; n < NR; ++n)
        acc[m][n] = __builtin_amdgcn_mfma_f32_16x16x32_bf16(a[m], b[n], acc[m][n], 0, 0, 0);
    cur ^= 1;
  }
  // epilogue: LDS-staged coalesced bf16 stores, 64 rows per pass
  ushort* Cs = (ushort*)smem;
#pragma unroll
  for (int half = 0; half < 2; ++half) {
    __syncthreads();
    if (wh == half) {
#pragma unroll
      for (int n = 0; n < NR; ++n) {
        int col = wn * WTN + n * 16 + r15;
        float bv = bias ? bias[bn + col] : 0.f;
#pragma unroll
        for (int m = 0; m < 2; ++m) {
#pragma unroll
          for (int j = 0; j < 4; ++j) {
            int row = wm * 32 + m * 16 + g4 * 4 + j;
            float v = acc[m][n][j] + bv;
            if (RELU) v = fmaxf(v, 0.f);
            Cs[row * CP + col] = f2b(v);
          }
        }
      }
    }
    __syncthreads();
    for (int it = tid; it < 64 * 32; it += 512) {
      int row = it >> 5, c8 = it & 31;
      int gr = bm + half * 64 + row;
      if (gr < M)
        *(ushort8*)(C + (size_t)gr * Nc + bn + c8 * 8) =
            *(const ushort8*)(Cs + row * CP + c8 * 8);
    }
  }
}

// ------------------------------ stage2: scan1 | Kmat | Vmat | embed ------------------------------
__global__ __launch_bounds__(256)
void stage2_k(const int* __restrict__ cnt, int* __restrict__ rowptr, int* __restrict__ bsum,
              const ushort* __restrict__ gcb, const ushort* __restrict__ WkT,
              const float* __restrict__ bk, ushort* __restrict__ Kmatb,
              const ushort* __restrict__ WvT, const float* __restrict__ bvv,
              ushort* __restrict__ Vmatb,
              const ushort* __restrict__ xb, const ushort* __restrict__ WpT,
              const float* __restrict__ bp, ushort* __restrict__ x_emb) {
  __shared__ __align__(16) char smem[65536];
  int b = blockIdx.x;
  if (b < 8) {
    gemm_body<128, false, true>(gcb, WkT, 256, nullptr, nullptr, 0, bk, Kmatb,
                                512, 256, b & 3, b >> 2, smem);
  } else if (b < 16) {
    int lb = b - 8;
    gemm_body<128, false, true>(gcb, WvT, 256, nullptr, nullptr, 0, bvv, Vmatb,
                                512, 256, lb & 3, lb >> 2, smem);
  } else if (b < 16 + EMB_MB) {
    gemm_body<64, true, true>(xb, WpT, 128, nullptr, nullptr, 0, bp, x_emb,
                              NN, 64, b - 16, 0, smem);
  } else {
    scan1_body(cnt, rowptr, bsum, NN, b - (16 + EMB_MB), smem);
  }
}

// ------------------------------ stage3: scan2 | KWqT | W_pv | sbias ------------------------------
__global__ __launch_bounds__(256)
void stage3_k(const ushort* __restrict__ Kmatb, const ushort* __restrict__ Wqb,
              ushort* __restrict__ KWqT,
              const ushort* __restrict__ Wm1bT, const ushort* __restrict__ Vmatb,
              ushort* __restrict__ W_pvT,
              const float* __restrict__ bq, float* __restrict__ sbias,
              const int* __restrict__ bsum, int* __restrict__ boff) {
  __shared__ __align__(16) char smem[65536];
  int b = blockIdx.x;
  if (b < 8) {
    gemm_body<128, false, true>(Kmatb, Wqb, 256, nullptr, nullptr, 0, nullptr, KWqT,
                                512, 256, b & 3, b >> 2, smem);
  } else if (b < 16) {
    int lb = b - 8;
    gemm_body<128, false, true>(Wm1bT, Vmatb, 256, nullptr, nullptr, 0, nullptr, W_pvT,
                                256, 512, lb & 1, lb >> 1, smem);
  } else if (b < 144) {
    sbias_body(bq, Kmatb, sbias, b - 16);
  } else {
    scan2_body(bsum, boff, NB1, smem);
  }
}

// ------------------------------ fused MLP + output head (BM=128 via 8 waves, BK=32, dbuf) ------------------------------
__global__ __launch_bounds__(512)
void mlp_out_k(const ushort* __restrict__ A1, const ushort* __restrict__ BT1, int K1,
               const ushort* __restrict__ A2, const ushort* __restrict__ BT2, int K2,
               const float* __restrict__ bias, const float* __restrict__ Wm2,
               const float* __restrict__ bm2, float* __restrict__ out, int M) {
  constexpr int NR = 8;              // 256 cols / 32
  constexpr int WTN = 128;           // wave col tile
  constexpr int ABYT = 128 * 32 * 2; // 8KB
  constexpr int BBYT = 256 * 32 * 2; // 16KB
  constexpr int BUF = ABYT + BBYT;   // 24KB
  __shared__ __align__(16) char smem[2 * BUF];   // 48KB
  const int tid = threadIdx.x;
  const int l = tid & 63;
  const int w = tid >> 6;            // 0..7
  const int wh = w >> 2;
  const int wm = (w >> 1) & 1, wn = w & 1;
  const int bm = blockIdx.x * 128;
  const int r15 = l & 15, g4 = l >> 4;

  const int nt1 = K1 >> 5;
  const int nt2 = K2 >> 5;
  const int nt = nt1 + nt2;

  auto STAGE = [&](int buf, int t) {
    const ushort* A = (t < nt1) ? A1 : A2;
    const ushort* BT = (t < nt1) ? BT1 : BT2;
    const int K = (t < nt1) ? K1 : K2;
    const int k0 = ((t < nt1) ? t : t - nt1) << 5;
    char* As = smem + buf * BUF;
    char* Bs = As + ABYT;
    {   // A: 128 rows x 4 slots = 512 chunks, 1/thread
      int row = tid >> 2, slot = tid & 3;
      int kb = slot ^ ((row >> 1) & 3);
      int grow = bm + row; if (grow >= M) grow = M - 1;
      gl_lds16(A + (size_t)grow * K + k0 + kb * 8, As + tid * 16);
    }
#pragma unroll
    for (int p = 0; p < 2; ++p) {   // B: 256 rows x 4 slots = 1024 chunks, 2/thread
      int idx = tid + p * 512;
      int row = idx >> 2, slot = idx & 3;
      int kb = slot ^ ((row >> 1) & 3);
      gl_lds16(BT + (size_t)row * K + k0 + kb * 8, Bs + idx * 16);
    }
  };

  f32x4 acc[2][NR];
  const f32x4 zz = {0.f, 0.f, 0.f, 0.f};
#pragma unroll
  for (int m = 0; m < 2; ++m)
#pragma unroll
    for (int n = 0; n < NR; ++n) acc[m][n] = zz;

  STAGE(0, 0);
  int cur = 0;
  for (int t = 0; t < nt; ++t) {
    __syncthreads();
    if (t + 1 < nt) STAGE(cur ^ 1, t + 1);
    const char* As = smem + cur * BUF;
    const char* Bs = As + ABYT;
    short8 a[2], b[NR];
#pragma unroll
    for (int m = 0; m < 2; ++m) {
      int row = wh * 64 + wm * 32 + m * 16 + r15;
      a[m] = *(const short8*)(As + row * 64 + ((g4 ^ ((row >> 1) & 3)) << 4));
    }
#pragma unroll
    for (int n = 0; n < NR; ++n) {
      int row = wn * WTN + n * 16 + r15;
      b[n] = *(const short8*)(Bs + row * 64 + ((g4 ^ ((row >> 1) & 3)) << 4));
    }
#pragma unroll
    for (int m = 0; m < 2; ++m)
#pragma unroll
      for (int n = 0; n < NR; ++n)
        acc[m][n] = __builtin_amdgcn_mfma_f32_16x16x32_bf16(a[m], b[n], acc[m][n], 0, 0, 0);
    cur ^= 1;
  }
  __syncthreads();
  float bv[NR], w20[NR], w21[NR];
#pragma unroll
  for (int n = 0; n < NR; ++n) {
    int col = wn * WTN + n * 16 + r15;
    bv[n] = bias[col];
    w20[n] = Wm2[col * 2 + 0];
    w21[n] = Wm2[col * 2 + 1];
  }
  float* red = (float*)smem;   // 2KB
#pragma unroll
  for (int m = 0; m < 2; ++m) {
#pragma unroll
    for (int j = 0; j < 4; ++j) {
      float p0 = 0.f, p1 = 0.f;
#pragma unroll
      for (int n = 0; n < NR; ++n) {
        float v = fmaxf(acc[m][n][j] + bv[n], 0.f);
        p0 += v * w20[n];
        p1 += v * w21[n];
      }
      p0 += __shfl_xor(p0, 1); p1 += __shfl_xor(p1, 1);
      p0 += __shfl_xor(p0, 2); p1 += __shfl_xor(p1, 2);
      p0 += __shfl_xor(p0, 4); p1 += __shfl_xor(p1, 4);
      p0 += __shfl_xor(p0, 8); p1 += __shfl_xor(p1, 8);
      if (r15 == 0) {
        int rl = wh * 64 + wm * 32 + m * 16 + g4 * 4 + j;
        red[wn * 256 + rl * 2 + 0] = p0;
        red[wn * 256 + rl * 2 + 1] = p1;
      }
    }
  }
  __syncthreads();
  if (tid < 256) {
    int rl = tid >> 1, j = tid & 1;   // 128 rows x 2 outputs
    int row = bm + rl;
    if (row < M)
      out[(size_t)row * 2 + j] = red[rl * 2 + j] + red[256 + rl * 2 + j] + bm2[j];
  }
}

// ------------------------------ softmax in place (pre-scaled bf16 logits -> bf16 P) ------------------------------
__global__ void softmax_k(ushort* __restrict__ SP, int M) {
  int row = blockIdx.x * 4 + (threadIdx.x >> 6);
  int lane = threadIdx.x & 63;
  if (row >= M) return;
  ushort4* p = (ushort4*)(SP + (size_t)row * 512);
  ushort4 ua = p[lane];
  ushort4 ub = p[lane + 64];
  float ax = b2f(ua.x), ay = b2f(ua.y), az = b2f(ua.z), aw = b2f(ua.w);
  float bx = b2f(ub.x), by = b2f(ub.y), bz = b2f(ub.z), bw = b2f(ub.w);
  float m = fmaxf(fmaxf(fmaxf(ax, ay), fmaxf(az, aw)),
                  fmaxf(fmaxf(bx, by), fmaxf(bz, bw)));
  for (int off = 32; off; off >>= 1) m = fmaxf(m, __shfl_xor(m, off));
  ax = expf(ax - m); ay = expf(ay - m); az = expf(az - m); aw = expf(aw - m);
  bx = expf(bx - m); by = expf(by - m); bz = expf(bz - m); bw = expf(bw - m);
  float s = ax + ay + az + aw + bx + by + bz + bw;
  for (int off = 32; off; off >>= 1) s += __shfl_xor(s, off);
  float inv = 1.f / s;
  ushort4 oa, ob;
  oa.x = f2b(ax * inv); oa.y = f2b(ay * inv); oa.z = f2b(az * inv); oa.w = f2b(aw * inv);
  ob.x = f2b(bx * inv); ob.y = f2b(by * inv); ob.z = f2b(bz * inv); ob.w = f2b(bw * inv);
  p[lane] = oa;
  p[lane + 64] = ob;
}

// ------------------------------ launch ------------------------------
extern "C" void kernel_launch(void* const* d_in, const int* in_sizes, int n_in,
                              void* d_out, int out_size, void* d_ws, size_t ws_size,
                              hipStream_t stream) {
  const int N = NN, E = NE;
  const float* x   = (const float*)d_in[0];
  const int*   ei  = (const int*)d_in[1];
  const float* gc  = (const float*)d_in[2];
  const float* Wp  = (const float*)d_in[3];
  const float* bp  = (const float*)d_in[4];
  const float* W1l = (const float*)d_in[5];
  const float* b1l = (const float*)d_in[6];
  const float* W1r = (const float*)d_in[7];
  const float* W2l = (const float*)d_in[8];
  const float* b2l = (const float*)d_in[9];
  const float* W2r = (const float*)d_in[10];
  const float* Wq  = (const float*)d_in[11];
  const float* bq  = (const float*)d_in[12];
  const float* Wk  = (const float*)d_in[13];
  const float* bk  = (const float*)d_in[14];
  const float* Wv  = (const float*)d_in[15];
  const float* bv  = (const float*)d_in[16];
  const float* Wm1 = (const float*)d_in[17];
  const float* bm1 = (const float*)d_in[18];
  const float* Wm2 = (const float*)d_in[19];
  const float* bm2 = (const float*)d_in[20];
  float* out = (float*)d_out;

  char* base = (char*)d_ws;
  size_t off = 0;
  auto take = [&](size_t bytes) -> void* {
    void* r = base + off;
    off += (bytes + 255) & ~(size_t)255;
    return r;
  };
  // CSR + misc
  int* cnt    = (int*)take((size_t)N * 4);
  int* rowptr = (int*)take((size_t)(N + 1) * 4);
  int* loc    = (int*)take((size_t)E * 4);
  int* eidx   = (int*)take((size_t)E * 4);
  int* eflag  = (int*)take(256);
  int* bsum   = (int*)take(NB1 * 4);
  int* boff   = (int*)take(NB1 * 4);
  // bf16 weights
  ushort* WpT   = (ushort*)take((size_t)64 * 128 * 2);
  ushort* W1lT  = (ushort*)take((size_t)256 * 64 * 2);
  ushort* W1rT  = (ushort*)take((size_t)256 * 64 * 2);
  ushort* W2lT  = (ushort*)take((size_t)256 * 256 * 2);
  ushort* W2rT  = (ushort*)take((size_t)256 * 256 * 2);
  ushort* WkT   = (ushort*)take((size_t)256 * 256 * 2);
  ushort* WvT   = (ushort*)take((size_t)256 * 256 * 2);
  ushort* Wqb   = (ushort*)take((size_t)256 * 256 * 2);
  ushort* Wm1aT = (ushort*)take((size_t)256 * 256 * 2);
  ushort* Wm1bT = (ushort*)take((size_t)256 * 256 * 2);
  // attention small
  ushort* gcb   = (ushort*)take((size_t)512 * 256 * 2);
  ushort* Kmatb = (ushort*)take((size_t)512 * 256 * 2);
  ushort* Vmatb = (ushort*)take((size_t)512 * 256 * 2);
  ushort* W_pvT = (ushort*)take((size_t)256 * 512 * 2);
  ushort* KWqT  = (ushort*)take((size_t)512 * 256 * 2);
  float*  sbias = (float*)take((size_t)512 * 4);
  // region U (full-size, single chunk): h2 [N*512B] + SP [N*1024B]; mean2
  // aliases SP lower half (dead before S written); pre-loop xb/x_emb/mean1
  // (N*512B total) fit in the h2 segment + start of SP.
  char* U = (char*)take((size_t)N * 1536);
  ushort* h = (ushort*)take((size_t)N * 256 * 2);   // live whole run
  if (off > ws_size) return;

  ushort* xb    = (ushort*)U;                           // N*256B (pre-loop)
  ushort* x_emb = (ushort*)(U + (size_t)N * 256);       // N*128B (pre-loop)
  ushort* mean1 = (ushort*)(U + (size_t)N * 384);       // N*128B (pre-loop)
  ushort* h2_c     = (ushort*)U;                        // N*512B
  ushort* SP_c     = (ushort*)(U + (size_t)N * 512);    // N*1024B (S then P)
  ushort* mean2_c  = SP_c;                              // aliases SP lower half

  const int n4 = N * 128 / 4;
  dim3 thr(256);
  dim3 thr512(512);

  // CvtJobs (Wqb pre-scaled by 1/16 to fold softmax scale)
  CvtJobs jb;
  {
    const float* s_[NJOB] = {gc, Wq, Wp, W1l, W1r, W2l, W2r, Wk, Wv, Wm1, Wm1};
    ushort* d_[NJOB] = {gcb, Wqb, WpT, W1lT, W1rT, W2lT, W2rT, WkT, WvT, Wm1aT, Wm1bT};
    int R_[NJOB] = {512, 256, 128, 64, 64, 256, 256, 256, 256, 256, 256};
    int C_[NJOB] = {256, 256, 64, 256, 256, 256, 256, 256, 256, 256, 256};
    int o_[NJOB] = {0, 0, 0, 0, 0, 0, 0, 0, 0, 0, 256};
    int t_[NJOB] = {0, 0, 1, 1, 1, 1, 1, 1, 1, 1, 1};
    for (int j = 0; j < NJOB; ++j) {
      jb.src[j] = s_[j]; jb.dst[j] = d_[j]; jb.R[j] = R_[j]; jb.C[j] = C_[j];
      jb.off[j] = o_[j]; jb.tr[j] = t_[j]; jb.sc[j] = (j == 1) ? 0.0625f : 1.0f;
    }
  }

  // CSR build + all conversions (count/x-cvt interleaved 1:4, w-cvt tail)
  zero_detect_k<<<1 + (N + 255) / 256, thr, 0, stream>>>(ei, eflag, cnt, N);
  count_cvt_k<<<CNTB + XCVB + WCVB, thr, 0, stream>>>(ei, eflag, cnt, loc, x, xb, E, n4, jb);
  // stage2: scan1 | Kmat | Vmat | embed (all depend only on count_cvt)
  stage2_k<<<16 + EMB_MB + NB1, thr, 0, stream>>>(
      cnt, rowptr, bsum, gcb, WkT, bk, Kmatb, WvT, bv, Vmatb, xb, WpT, bp, x_emb);
  // stage3: scan2 | KWqT | W_pv | sbias (all depend only on stage2)
  stage3_k<<<145, thr, 0, stream>>>(
      Kmatb, Wqb, KWqT, Wm1bT, Vmatb, W_pvT, bq, sbias, bsum, boff);
  scan3_k<<<(N + 255) / 256, thr, 0, stream>>>(rowptr, boff, N);
  fill_edges_k<<<(E + 255) / 256, thr, 0, stream>>>(ei, eflag, rowptr, loc, eidx, E);

  // SAGE1 (8-wave BM=128/BK=32 shape)
  agg64_k<<<(N + 3) / 4, thr, 0, stream>>>(x_emb, rowptr, eidx, mean1, 0, N);
  gemm64_k<true><<<dim3((N + 127) / 128, 1), thr512, 0, stream>>>(
      mean1, W1lT, 64, x_emb, W1rT, 64, b1l, h, N, 256);

  // single-pass SAGE2 + attention + fused MLP/out (PV folded via W_pv)
  {
    const int CRc = N;
    const int MBc128 = (CRc + 127) / 128;
    agg256_k<<<(CRc + 3) / 4, thr, 0, stream>>>(h, rowptr, eidx, mean2_c, 0, CRc);
    gemm64_k<false><<<dim3(MBc128, 1), thr512, 0, stream>>>(
        mean2_c, W2lT, 256, h, W2rT, 256, b2l, h2_c, CRc, 256);
    gemm64_k<false><<<dim3(MBc128, 2), thr512, 0, stream>>>(
        h2_c, KWqT, 256, nullptr, nullptr, 0, sbias, SP_c, CRc, 512);
    softmax_k<<<(CRc + 3) / 4, thr, 0, stream>>>(SP_c, CRc);
    mlp_out_k<<<dim3(MBc128, 1), thr512, 0, stream>>>(
        h2_c, Wm1aT, 256, SP_c, W_pvT, 512, bm1, Wm2, bm2, out, CRc);
  }
}

// Round 30
// 391.191 us; speedup vs baseline: 1.3492x; 1.0183x over previous
//
#include <hip/hip_runtime.h>
#include <cstdint>
#include <cstddef>

// GAAPModelB on MI355X: bf16-MFMA GEMM stack + CSR gather aggregation.
// N=100000, E=800000, IN=128, H=256, G=512.
// R30 (= R29 + two bit-identical tweaks):
//  1. gemm64 grid swapped (bn on x, bm on y): S-GEMM's two bn-halves of the
//     same bm dispatch adjacently -> A-tile L2 reuse (FETCH ~halves).
//  2. agg64 2-deep gather pipeline (order-preserving, like R29's agg256).

#define NN 100000
#define NE 800000
#define CR 100000  // single chunk
#define NB1 98     // ceil(100000/1024) scan blocks
#define CNTB 3125  // count-role blocks (1 in 5 of first 15625)
#define XCVB 12500 // x-cvt-role blocks
#define NJOB 11
#define WCVB (NJOB * 32)
#define EMB_MB 782 // ceil(100000/128)

typedef __attribute__((ext_vector_type(8))) short short8;
typedef __attribute__((ext_vector_type(8))) unsigned short ushort8;
typedef __attribute__((ext_vector_type(4))) float f32x4;

__device__ __forceinline__ float b2f(ushort u) {
  union { unsigned u; float f; } v; v.u = ((unsigned)u) << 16; return v.f;
}
__device__ __forceinline__ ushort f2b(float f) {
  union { float f; unsigned u; } v; v.f = f;
  unsigned r = v.u + 0x7FFFu + ((v.u >> 16) & 1u);
  return (ushort)(r >> 16);
}
__device__ __forceinline__ void gl_lds16(const void* g, void* l) {
  __builtin_amdgcn_global_load_lds((const __attribute__((address_space(1))) void*)g,
                                   (__attribute__((address_space(3))) void*)l, 16, 0, 0);
}

// ------------------------------ utility ------------------------------
// block 0: detect int64 edge layout; blocks 1..: zero cnt
__global__ void zero_detect_k(const int* __restrict__ ei, int* __restrict__ flag,
                              int* __restrict__ cnt, int n) {
  if (blockIdx.x == 0) {
    __shared__ int ok;
    int t = threadIdx.x;
    if (t == 0) ok = 1;
    __syncthreads();
    if (ei[2 * t + 1] != 0) ok = 0;
    __syncthreads();
    if (t == 0) *flag = ok;
  } else {
    int i = (blockIdx.x - 1) * 256 + threadIdx.x;
    if (i < n) cnt[i] = 0;
  }
}

struct CvtJobs {
  const float* src[NJOB];
  ushort* dst[NJOB];
  int R[NJOB], C[NJOB], off[NJOB], tr[NJOB];
  float sc[NJOB];
};

// ------------------------------ CSR build + conversions (3 roles, interleaved) ------------------------------
__global__ void count_cvt_k(const int* __restrict__ ei, const int* __restrict__ flag,
                            int* __restrict__ cnt, int* __restrict__ loc,
                            const float* __restrict__ x, ushort* __restrict__ xb,
                            int E, int n4, CvtJobs jb) {
  int b = blockIdx.x;
  if (b < CNTB + XCVB) {
    int q = b / 5;
    if (b - q * 5 == 0) {
      int i = q * 256 + threadIdx.x;
      if (i >= E) return;
      const bool i64 = (*flag != 0);
      unsigned d = (unsigned)(i64 ? ei[2 * E + 2 * i] : ei[E + i]);
      int p = -1;
      if (d < NN) p = atomicAdd(&cnt[d], 1);
      loc[i] = p;
    } else {
      int i = (b - q - 1) * 256 + threadIdx.x;
      if (i < n4) {
        float4 v = ((const float4*)x)[i];
        ushort4 o; o.x = f2b(v.x); o.y = f2b(v.y); o.z = f2b(v.z); o.w = f2b(v.w);
        ((ushort4*)xb)[i] = o;
      }
    }
  } else {
    int wb = b - CNTB - XCVB;
    int j = wb >> 5;            // job
    int ib = wb & 31;           // inner block
    const int Cj = jb.C[j], Rj = jb.R[j];
    const float sc = jb.sc[j];
    const int n = Rj * Cj;
    if (jb.tr[j]) {
      for (int i = ib * 256 + threadIdx.x; i < n; i += 32 * 256) {
        int c = i / Rj, r = i - c * Rj;
        jb.dst[j][i] = f2b(jb.src[j][(size_t)(jb.off[j] + r) * Cj + c] * sc);
      }
    } else {
      for (int i = ib * 256 + threadIdx.x; i < n; i += 32 * 256)
        jb.dst[j][i] = f2b(jb.src[j][i] * sc);
    }
  }
}

// ------------------------------ scan bodies ------------------------------
__device__ __forceinline__ void scan1_body(const int* __restrict__ cnt,
                                           int* __restrict__ rowptr,
                                           int* __restrict__ bsum, int n, int b,
                                           char* smem) {
  int* ls = (int*)smem;
  const int t = threadIdx.x;
  const int base = b * 1024 + t * 4;
  int v[4]; int s = 0;
#pragma unroll
  for (int j = 0; j < 4; ++j) { int i = base + j; v[j] = (i < n) ? cnt[i] : 0; s += v[j]; }
  ls[t] = s; __syncthreads();
  int x = s;
  for (int o = 1; o < 256; o <<= 1) {
    int a = (t >= o) ? ls[t - o] : 0; __syncthreads();
    x += a; ls[t] = x; __syncthreads();
  }
  int run = x - s;
#pragma unroll
  for (int j = 0; j < 4; ++j) { run += v[j]; int i = base + j; if (i < n) rowptr[i + 1] = run; }
  if (t == 255) bsum[b] = x;
}

__device__ __forceinline__ void scan2_body(const int* __restrict__ bsum,
                                           int* __restrict__ boff, int nb,
                                           char* smem) {
  int* ls = (int*)smem;
  int t = threadIdx.x;
  int v = (t < 128 && t < nb) ? bsum[t] : 0;
  if (t < 128) ls[t] = v;
  __syncthreads();
  int x = v;
  for (int o = 1; o < 128; o <<= 1) {
    int a = (t < 128 && t >= o) ? ls[t - o] : 0;
    __syncthreads();
    x += a;
    if (t < 128) ls[t] = x;
    __syncthreads();
  }
  if (t < 128 && t < nb) boff[t] = x - v;
}

__device__ __forceinline__ void sbias_body(const float* __restrict__ bq,
                                           const ushort* __restrict__ Kmat,
                                           float* __restrict__ sbias, int blk) {
  int g = blk * 4 + (threadIdx.x >> 6);
  int lane = threadIdx.x & 63;
  if (g >= 512) return;
  ushort4 kv = ((const ushort4*)(Kmat + (size_t)g * 256))[lane];
  float4 bv = ((const float4*)bq)[lane];
  float p = b2f(kv.x) * bv.x + b2f(kv.y) * bv.y + b2f(kv.z) * bv.z + b2f(kv.w) * bv.w;
  for (int off = 32; off; off >>= 1) p += __shfl_xor(p, off);
  if (lane == 0) sbias[g] = p * 0.0625f;
}

__global__ void scan3_k(int* __restrict__ rowptr, const int* __restrict__ boff, int n) {
  int i = blockIdx.x * 256 + threadIdx.x;
  if (i == 0) rowptr[0] = 0;
  if (i < n) rowptr[i + 1] += boff[i >> 10];
}

// atomic-free fill: position = rowptr[d] + loc[i]
__global__ void fill_edges_k(const int* __restrict__ ei, const int* __restrict__ flag,
                             const int* __restrict__ rowptr, const int* __restrict__ loc,
                             int* __restrict__ eidx, int E) {
  int i = blockIdx.x * 256 + threadIdx.x;
  if (i >= E) return;
  const bool i64 = (*flag != 0);
  unsigned s = (unsigned)(i64 ? ei[2 * i] : ei[i]);
  unsigned d = (unsigned)(i64 ? ei[2 * E + 2 * i] : ei[E + i]);
  int lc = loc[i];
  if (d < NN && s < NN && lc >= 0) {
    unsigned p = (unsigned)(rowptr[d] + lc);
    if (p < (unsigned)E) eidx[p] = (int)s;
  }
}

// ------------------------------ aggregation ------------------------------
// R30: 2-deep gather pipeline per lane; accumulation order preserved
// (i then i+4 into the same accumulators) -> bit-identical.
__global__ void agg64_k(const ushort* __restrict__ X, const int* __restrict__ rowptr,
                        const int* __restrict__ eidx, ushort* __restrict__ mean,
                        int r0, int M) {
  int nl = blockIdx.x * 4 + (threadIdx.x >> 6);
  int l = threadIdx.x & 63;
  int e4 = l >> 4;      // edge slot 0..3
  int d4 = l & 15;      // dim group (4 dims)
  if (nl >= M) return;
  int node = r0 + nl;
  int s = rowptr[node], e = rowptr[node + 1];
  float a0 = 0.f, a1 = 0.f, a2 = 0.f, a3 = 0.f;
  for (int i = s + e4; i < e; i += 8) {
    int j1 = (i + 4 < e) ? i + 4 : i;
    unsigned id0 = (unsigned)eidx[i];
    unsigned id1 = (unsigned)eidx[j1];
    ushort4 v0 = ((const ushort4*)(X + (size_t)(id0 < NN ? id0 : 0u) * 64))[d4];
    ushort4 v1 = ((const ushort4*)(X + (size_t)(id1 < NN ? id1 : 0u) * 64))[d4];
    if (id0 < NN) {
      a0 += b2f(v0.x); a1 += b2f(v0.y); a2 += b2f(v0.z); a3 += b2f(v0.w);
    }
    if (i + 4 < e && id1 < NN) {
      a0 += b2f(v1.x); a1 += b2f(v1.y); a2 += b2f(v1.z); a3 += b2f(v1.w);
    }
  }
  a0 += __shfl_xor(a0, 16); a0 += __shfl_xor(a0, 32);
  a1 += __shfl_xor(a1, 16); a1 += __shfl_xor(a1, 32);
  a2 += __shfl_xor(a2, 16); a2 += __shfl_xor(a2, 32);
  a3 += __shfl_xor(a3, 16); a3 += __shfl_xor(a3, 32);
  if (e4 == 0) {
    float inv = 1.f / (float)max(e - s, 1);
    ushort4 o; o.x = f2b(a0 * inv); o.y = f2b(a1 * inv); o.z = f2b(a2 * inv); o.w = f2b(a3 * inv);
    ((ushort4*)(mean + (size_t)nl * 64))[d4] = o;
  }
}

// R29: 4 gather loads in flight per lane; accumulation ORDER preserved vs
// R28 (a: i, i+4, ...; c: i+2, i+6, ...) -> bit-identical output.
__global__ void agg256_k(const ushort* __restrict__ X, const int* __restrict__ rowptr,
                         const int* __restrict__ eidx, ushort* __restrict__ mean,
                         int r0, int M) {
  int nl = blockIdx.x * 4 + (threadIdx.x >> 6);
  int l = threadIdx.x & 63;
  int g = l >> 5;       // edge slot parity 0..1
  int d = l & 31;       // 8-dim group
  if (nl >= M) return;
  int node = r0 + nl;
  int s = rowptr[node], e = rowptr[node + 1];
  float a[8], c[8];
#pragma unroll
  for (int k = 0; k < 8; ++k) { a[k] = 0.f; c[k] = 0.f; }
  for (int i = s + g; i < e; i += 8) {
    // clamp tail indices to a valid slot (predicated accumulation below)
    int j1 = (i + 2 < e) ? i + 2 : i;
    int j2 = (i + 4 < e) ? i + 4 : i;
    int j3 = (i + 6 < e) ? i + 6 : i;
    unsigned id0 = (unsigned)eidx[i];
    unsigned id1 = (unsigned)eidx[j1];
    unsigned id2 = (unsigned)eidx[j2];
    unsigned id3 = (unsigned)eidx[j3];
    ushort8 v0 = *(const ushort8*)(X + (size_t)(id0 < NN ? id0 : 0u) * 256 + d * 8);
    ushort8 v1 = *(const ushort8*)(X + (size_t)(id1 < NN ? id1 : 0u) * 256 + d * 8);
    ushort8 v2 = *(const ushort8*)(X + (size_t)(id2 < NN ? id2 : 0u) * 256 + d * 8);
    ushort8 v3 = *(const ushort8*)(X + (size_t)(id3 < NN ? id3 : 0u) * 256 + d * 8);
    if (id0 < NN) {
#pragma unroll
      for (int k = 0; k < 8; ++k) a[k] += b2f((ushort)v0[k]);
    }
    if (i + 2 < e && id1 < NN) {
#pragma unroll
      for (int k = 0; k < 8; ++k) c[k] += b2f((ushort)v1[k]);
    }
    if (i + 4 < e && id2 < NN) {
#pragma unroll
      for (int k = 0; k < 8; ++k) a[k] += b2f((ushort)v2[k]);
    }
    if (i + 6 < e && id3 < NN) {
#pragma unroll
      for (int k = 0; k < 8; ++k) c[k] += b2f((ushort)v3[k]);
    }
  }
  float inv = 1.f / (float)max(e - s, 1);
  ushort8 o;
#pragma unroll
  for (int k = 0; k < 8; ++k) {
    float t = a[k] + c[k];
    t += __shfl_xor(t, 32);
    o[k] = (short)f2b(t * inv);
  }
  if (g == 0) *(ushort8*)(mean + (size_t)nl * 256 + d * 8) = o;
}

// ------------------------------ bf16 MFMA GEMM body (2-phase dbuf, BM=128/BK=64) ------------------------------
// used by stage2/stage3 pre-kernels only
template<int BN, bool RELU, bool OUTBF>
__device__ __forceinline__ void gemm_body(
    const ushort* __restrict__ A1, const ushort* __restrict__ BT1, int K1,
    const ushort* __restrict__ A2, const ushort* __restrict__ BT2, int K2,
    const float* __restrict__ bias, void* __restrict__ Cv, int M, int Nc,
    int bmi, int bni, char* smem) {
  constexpr int NR = BN / 32;
  constexpr int WTN = BN / 2;
  constexpr int ABYT = 128 * 64 * 2;
  constexpr int BBYT = BN * 64 * 2;
  constexpr int BUF = ABYT + BBYT;
  constexpr int CP = BN + 8;
  const int tid = threadIdx.x;
  const int l = tid & 63;
  const int w = tid >> 6;
  const int wm = w >> 1, wn = w & 1;
  const int bm = bmi * 128, bn = bni * BN;
  const int r15 = l & 15, g4 = l >> 4;

  const int nt1 = K1 >> 6;
  const int nt2 = A2 ? (K2 >> 6) : 0;
  const int nt = nt1 + nt2;

  auto STAGE = [&](int buf, int t) {
    const ushort* A = (t < nt1) ? A1 : A2;
    const ushort* BT = (t < nt1) ? BT1 : BT2;
    const int K = (t < nt1) ? K1 : K2;
    const int k0 = ((t < nt1) ? t : t - nt1) << 6;
    char* As = smem + buf * BUF;
    char* Bs = As + ABYT;
#pragma unroll
    for (int p = 0; p < 4; ++p) {
      int idx = tid + p * 256;
      int row = idx >> 3, slot = idx & 7;
      int kb = slot ^ (row & 7);
      int grow = bm + row; if (grow >= M) grow = M - 1;
      gl_lds16(A + (size_t)grow * K + k0 + kb * 8, As + idx * 16);
    }
#pragma unroll
    for (int p = 0; p < BN / 32; ++p) {
      int idx = tid + p * 256;
      int row = idx >> 3, slot = idx & 7;
      int kb = slot ^ (row & 7);
      gl_lds16(BT + (size_t)(bn + row) * K + k0 + kb * 8, Bs + idx * 16);
    }
  };

  f32x4 acc[4][NR];
  const f32x4 zz = {0.f, 0.f, 0.f, 0.f};
#pragma unroll
  for (int m = 0; m < 4; ++m)
#pragma unroll
    for (int n = 0; n < NR; ++n) acc[m][n] = zz;

  STAGE(0, 0);
  int cur = 0;
  for (int t = 0; t < nt; ++t) {
    __syncthreads();
    if (t + 1 < nt) STAGE(cur ^ 1, t + 1);
    const char* As = smem + cur * BUF;
    const char* Bs = As + ABYT;
#pragma unroll
    for (int s = 0; s < 2; ++s) {
      short8 a[4], b[NR];
      const int slotx = (((s * 4 + g4) ^ (r15 & 7)) << 4);
#pragma unroll
      for (int m = 0; m < 4; ++m) {
        int row = wm * 64 + m * 16 + r15;
        a[m] = *(const short8*)(As + row * 128 + slotx);
      }
#pragma unroll
      for (int n = 0; n < NR; ++n) {
        int row = wn * WTN + n * 16 + r15;
        b[n] = *(const short8*)(Bs + row * 128 + slotx);
      }
#pragma unroll
      for (int m = 0; m < 4; ++m)
#pragma unroll
        for (int n = 0; n < NR; ++n)
          acc[m][n] = __builtin_amdgcn_mfma_f32_16x16x32_bf16(a[m], b[n], acc[m][n], 0, 0, 0);
    }
    cur ^= 1;
  }
  __syncthreads();
  if (OUTBF) {
    ushort* Cs = (ushort*)smem;
#pragma unroll
    for (int n = 0; n < NR; ++n) {
      int col = wn * WTN + n * 16 + r15;
      float bv = bias ? bias[bn + col] : 0.f;
#pragma unroll
      for (int m = 0; m < 4; ++m) {
#pragma unroll
        for (int j = 0; j < 4; ++j) {
          int row = wm * 64 + m * 16 + g4 * 4 + j;
          float v = acc[m][n][j] + bv;
          if (RELU) v = fmaxf(v, 0.f);
          Cs[row * CP + col] = f2b(v);
        }
      }
    }
    __syncthreads();
    constexpr int C8 = BN / 8;
    for (int it = tid; it < 128 * C8; it += 256) {
      int row = it / C8, c8 = it % C8;
      if (bm + row < M)
        *(ushort8*)((ushort*)Cv + (size_t)(bm + row) * Nc + bn + c8 * 8) =
            *(const ushort8*)(Cs + row * CP + c8 * 8);
    }
  } else {
#pragma unroll
    for (int n = 0; n < NR; ++n) {
      int col = bn + wn * WTN + n * 16 + r15;
      float bv = bias ? bias[col] : 0.f;
#pragma unroll
      for (int m = 0; m < 4; ++m) {
#pragma unroll
        for (int j = 0; j < 4; ++j) {
          int row = bm + wm * 64 + m * 16 + g4 * 4 + j;
          if (row < M) {
            float v = acc[m][n][j] + bv;
            if (RELU) v = fmaxf(v, 0.f);
            ((float*)Cv)[(size_t)row * Nc + col] = v;
          }
        }
      }
    }
  }
}

// ------------------------------ bf16 MFMA GEMM (BM=128 via 8 waves, BK=32, BN=256/grid.x, dbuf) ------------------------------
// R30: bn on blockIdx.x (fastest), bm on blockIdx.y -> for Nc=512 the two
// bn-halves of the same bm dispatch adjacently (A-tile L2 reuse).
template<bool RELU>
__global__ __launch_bounds__(512)
void gemm64_k(const ushort* __restrict__ A1, const ushort* __restrict__ BT1, int K1,
              const ushort* __restrict__ A2, const ushort* __restrict__ BT2, int K2,
              const float* __restrict__ bias, ushort* __restrict__ C, int M, int Nc) {
  constexpr int NR = 8;              // 256 cols / 32
  constexpr int WTN = 128;           // wave col tile
  constexpr int ABYT = 128 * 32 * 2; // 8KB
  constexpr int BBYT = 256 * 32 * 2; // 16KB
  constexpr int BUF = ABYT + BBYT;   // 24KB
  constexpr int CP = 256 + 8;
  __shared__ __align__(16) char smem[2 * BUF];   // 48KB
  const int tid = threadIdx.x;
  const int l = tid & 63;
  const int w = tid >> 6;            // 0..7
  const int wh = w >> 2;             // half: rows [wh*64, wh*64+64)
  const int wm = (w >> 1) & 1, wn = w & 1;
  const int bm = blockIdx.y * 128;
  const int bn = blockIdx.x * 256;
  const int r15 = l & 15, g4 = l >> 4;

  const int nt1 = K1 >> 5;
  const int nt2 = A2 ? (K2 >> 5) : 0;
  const int nt = nt1 + nt2;

  auto STAGE = [&](int buf, int t) {
    const ushort* A = (t < nt1) ? A1 : A2;
    const ushort* BT = (t < nt1) ? BT1 : BT2;
    const int K = (t < nt1) ? K1 : K2;
    const int k0 = ((t < nt1) ? t : t - nt1) << 5;
    char* As = smem + buf * BUF;
    char* Bs = As + ABYT;
    {   // A: 128 rows x 4 slots = 512 chunks, 1/thread
      int row = tid >> 2, slot = tid & 3;
      int kb = slot ^ ((row >> 1) & 3);
      int grow = bm + row; if (grow >= M) grow = M - 1;
      gl_lds16(A + (size_t)grow * K + k0 + kb * 8, As + tid * 16);
    }
#pragma unroll
    for (int p = 0; p < 2; ++p) {   // B: 256 rows x 4 slots = 1024 chunks, 2/thread
      int idx = tid + p * 512;
      int row = idx >> 2, slot = idx & 3;
      int kb = slot ^ ((row >> 1) & 3);
      gl_lds16(BT + (size_t)(bn + row) * K + k0 + kb * 8, Bs + idx * 16);
    }
  };

  f32x4 acc[2][NR];
  const f32x4 zz = {0.f, 0.f, 0.f, 0.f};
#pragma unroll
  for (int m = 0; m < 2; ++m)
#pragma unroll
    for (int n = 0; n < NR; ++n) acc[m][n] = zz;

  STAGE(0, 0);
  int cur = 0;
  for (int t = 0; t < nt; ++t) {
    __syncthreads();
    if (t + 1 < nt) STAGE(cur ^ 1, t + 1);
    const char* As = smem + cur * BUF;
    const char* Bs = As + ABYT;
    short8 a[2], b[NR];
#pragma unroll
    for (int m = 0; m < 2; ++m) {
      int row = wh * 64 + wm * 32 + m * 16 + r15;
      a[m] = *(const short8*)(As + row * 64 + ((g4 ^ ((row >> 1) & 3)) << 4));
    }
#pragma unroll
    for (int n = 0; n < NR; ++n) {
      int row = wn * WTN + n * 16 + r15;
      b[n] = *(const short8*)(Bs + row * 64 + ((g4 ^ ((row >> 1) & 3)) << 4));
    }
#pragma unroll
    for (int m = 0; m < 2; ++m)
#pragma unroll
      for (int n = 0; n < NR; ++n)
        acc[m][n] = __builtin_amdgcn_mfma_f32_16x16x32_bf16(a[m], b[n], acc[m][n], 0, 0, 0);
    cur ^= 1;
  }
  // epilogue: LDS-staged coalesced bf16 stores, 64 rows per pass
  ushort* Cs = (ushort*)smem;
#pragma unroll
  for (int half = 0; half < 2; ++half) {
    __syncthreads();
    if (wh == half) {
#pragma unroll
      for (int n = 0; n < NR; ++n) {
        int col = wn * WTN + n * 16 + r15;
        float bv = bias ? bias[bn + col] : 0.f;
#pragma unroll
        for (int m = 0; m < 2; ++m) {
#pragma unroll
          for (int j = 0; j < 4; ++j) {
            int row = wm * 32 + m * 16 + g4 * 4 + j;
            float v = acc[m][n][j] + bv;
            if (RELU) v = fmaxf(v, 0.f);
            Cs[row * CP + col] = f2b(v);
          }
        }
      }
    }
    __syncthreads();
    for (int it = tid; it < 64 * 32; it += 512) {
      int row = it >> 5, c8 = it & 31;
      int gr = bm + half * 64 + row;
      if (gr < M)
        *(ushort8*)(C + (size_t)gr * Nc + bn + c8 * 8) =
            *(const ushort8*)(Cs + row * CP + c8 * 8);
    }
  }
}

// ------------------------------ stage2: scan1 | Kmat | Vmat | embed ------------------------------
__global__ __launch_bounds__(256)
void stage2_k(const int* __restrict__ cnt, int* __restrict__ rowptr, int* __restrict__ bsum,
              const ushort* __restrict__ gcb, const ushort* __restrict__ WkT,
              const float* __restrict__ bk, ushort* __restrict__ Kmatb,
              const ushort* __restrict__ WvT, const float* __restrict__ bvv,
              ushort* __restrict__ Vmatb,
              const ushort* __restrict__ xb, const ushort* __restrict__ WpT,
              const float* __restrict__ bp, ushort* __restrict__ x_emb) {
  __shared__ __align__(16) char smem[65536];
  int b = blockIdx.x;
  if (b < 8) {
    gemm_body<128, false, true>(gcb, WkT, 256, nullptr, nullptr, 0, bk, Kmatb,
                                512, 256, b & 3, b >> 2, smem);
  } else if (b < 16) {
    int lb = b - 8;
    gemm_body<128, false, true>(gcb, WvT, 256, nullptr, nullptr, 0, bvv, Vmatb,
                                512, 256, lb & 3, lb >> 2, smem);
  } else if (b < 16 + EMB_MB) {
    gemm_body<64, true, true>(xb, WpT, 128, nullptr, nullptr, 0, bp, x_emb,
                              NN, 64, b - 16, 0, smem);
  } else {
    scan1_body(cnt, rowptr, bsum, NN, b - (16 + EMB_MB), smem);
  }
}

// ------------------------------ stage3: scan2 | KWqT | W_pv | sbias ------------------------------
__global__ __launch_bounds__(256)
void stage3_k(const ushort* __restrict__ Kmatb, const ushort* __restrict__ Wqb,
              ushort* __restrict__ KWqT,
              const ushort* __restrict__ Wm1bT, const ushort* __restrict__ Vmatb,
              ushort* __restrict__ W_pvT,
              const float* __restrict__ bq, float* __restrict__ sbias,
              const int* __restrict__ bsum, int* __restrict__ boff) {
  __shared__ __align__(16) char smem[65536];
  int b = blockIdx.x;
  if (b < 8) {
    gemm_body<128, false, true>(Kmatb, Wqb, 256, nullptr, nullptr, 0, nullptr, KWqT,
                                512, 256, b & 3, b >> 2, smem);
  } else if (b < 16) {
    int lb = b - 8;
    gemm_body<128, false, true>(Wm1bT, Vmatb, 256, nullptr, nullptr, 0, nullptr, W_pvT,
                                256, 512, lb & 1, lb >> 1, smem);
  } else if (b < 144) {
    sbias_body(bq, Kmatb, sbias, b - 16);
  } else {
    scan2_body(bsum, boff, NB1, smem);
  }
}

// ------------------------------ fused MLP + output head (BM=128 via 8 waves, BK=32, dbuf) ------------------------------
__global__ __launch_bounds__(512)
void mlp_out_k(const ushort* __restrict__ A1, const ushort* __restrict__ BT1, int K1,
               const ushort* __restrict__ A2, const ushort* __restrict__ BT2, int K2,
               const float* __restrict__ bias, const float* __restrict__ Wm2,
               const float* __restrict__ bm2, float* __restrict__ out, int M) {
  constexpr int NR = 8;              // 256 cols / 32
  constexpr int WTN = 128;           // wave col tile
  constexpr int ABYT = 128 * 32 * 2; // 8KB
  constexpr int BBYT = 256 * 32 * 2; // 16KB
  constexpr int BUF = ABYT + BBYT;   // 24KB
  __shared__ __align__(16) char smem[2 * BUF];   // 48KB
  const int tid = threadIdx.x;
  const int l = tid & 63;
  const int w = tid >> 6;            // 0..7
  const int wh = w >> 2;
  const int wm = (w >> 1) & 1, wn = w & 1;
  const int bm = blockIdx.x * 128;
  const int r15 = l & 15, g4 = l >> 4;

  const int nt1 = K1 >> 5;
  const int nt2 = K2 >> 5;
  const int nt = nt1 + nt2;

  auto STAGE = [&](int buf, int t) {
    const ushort* A = (t < nt1) ? A1 : A2;
    const ushort* BT = (t < nt1) ? BT1 : BT2;
    const int K = (t < nt1) ? K1 : K2;
    const int k0 = ((t < nt1) ? t : t - nt1) << 5;
    char* As = smem + buf * BUF;
    char* Bs = As + ABYT;
    {   // A: 128 rows x 4 slots = 512 chunks, 1/thread
      int row = tid >> 2, slot = tid & 3;
      int kb = slot ^ ((row >> 1) & 3);
      int grow = bm + row; if (grow >= M) grow = M - 1;
      gl_lds16(A + (size_t)grow * K + k0 + kb * 8, As + tid * 16);
    }
#pragma unroll
    for (int p = 0; p < 2; ++p) {   // B: 256 rows x 4 slots = 1024 chunks, 2/thread
      int idx = tid + p * 512;
      int row = idx >> 2, slot = idx & 3;
      int kb = slot ^ ((row >> 1) & 3);
      gl_lds16(BT + (size_t)row * K + k0 + kb * 8, Bs + idx * 16);
    }
  };

  f32x4 acc[2][NR];
  const f32x4 zz = {0.f, 0.f, 0.f, 0.f};
#pragma unroll
  for (int m = 0; m < 2; ++m)
#pragma unroll
    for (int n = 0; n < NR; ++n) acc[m][n] = zz;

  STAGE(0, 0);
  int cur = 0;
  for (int t = 0; t < nt; ++t) {
    __syncthreads();
    if (t + 1 < nt) STAGE(cur ^ 1, t + 1);
    const char* As = smem + cur * BUF;
    const char* Bs = As + ABYT;
    short8 a[2], b[NR];
#pragma unroll
    for (int m = 0; m < 2; ++m) {
      int row = wh * 64 + wm * 32 + m * 16 + r15;
      a[m] = *(const short8*)(As + row * 64 + ((g4 ^ ((row >> 1) & 3)) << 4));
    }
#pragma unroll
    for (int n = 0; n < NR; ++n) {
      int row = wn * WTN + n * 16 + r15;
      b[n] = *(const short8*)(Bs + row * 64 + ((g4 ^ ((row >> 1) & 3)) << 4));
    }
#pragma unroll
    for (int m = 0; m < 2; ++m)
#pragma unroll
      for (int n = 0; n < NR; ++n)
        acc[m][n] = __builtin_amdgcn_mfma_f32_16x16x32_bf16(a[m], b[n], acc[m][n], 0, 0, 0);
    cur ^= 1;
  }
  __syncthreads();
  float bv[NR], w20[NR], w21[NR];
#pragma unroll
  for (int n = 0; n < NR; ++n) {
    int col = wn * WTN + n * 16 + r15;
    bv[n] = bias[col];
    w20[n] = Wm2[col * 2 + 0];
    w21[n] = Wm2[col * 2 + 1];
  }
  float* red = (float*)smem;   // 2KB
#pragma unroll
  for (int m = 0; m < 2; ++m) {
#pragma unroll
    for (int j = 0; j < 4; ++j) {
      float p0 = 0.f, p1 = 0.f;
#pragma unroll
      for (int n = 0; n < NR; ++n) {
        float v = fmaxf(acc[m][n][j] + bv[n], 0.f);
        p0 += v * w20[n];
        p1 += v * w21[n];
      }
      p0 += __shfl_xor(p0, 1); p1 += __shfl_xor(p1, 1);
      p0 += __shfl_xor(p0, 2); p1 += __shfl_xor(p1, 2);
      p0 += __shfl_xor(p0, 4); p1 += __shfl_xor(p1, 4);
      p0 += __shfl_xor(p0, 8); p1 += __shfl_xor(p1, 8);
      if (r15 == 0) {
        int rl = wh * 64 + wm * 32 + m * 16 + g4 * 4 + j;
        red[wn * 256 + rl * 2 + 0] = p0;
        red[wn * 256 + rl * 2 + 1] = p1;
      }
    }
  }
  __syncthreads();
  if (tid < 256) {
    int rl = tid >> 1, j = tid & 1;   // 128 rows x 2 outputs
    int row = bm + rl;
    if (row < M)
      out[(size_t)row * 2 + j] = red[rl * 2 + j] + red[256 + rl * 2 + j] + bm2[j];
  }
}

// ------------------------------ softmax in place (pre-scaled bf16 logits -> bf16 P) ------------------------------
__global__ void softmax_k(ushort* __restrict__ SP, int M) {
  int row = blockIdx.x * 4 + (threadIdx.x >> 6);
  int lane = threadIdx.x & 63;
  if (row >= M) return;
  ushort4* p = (ushort4*)(SP + (size_t)row * 512);
  ushort4 ua = p[lane];
  ushort4 ub = p[lane + 64];
  float ax = b2f(ua.x), ay = b2f(ua.y), az = b2f(ua.z), aw = b2f(ua.w);
  float bx = b2f(ub.x), by = b2f(ub.y), bz = b2f(ub.z), bw = b2f(ub.w);
  float m = fmaxf(fmaxf(fmaxf(ax, ay), fmaxf(az, aw)),
                  fmaxf(fmaxf(bx, by), fmaxf(bz, bw)));
  for (int off = 32; off; off >>= 1) m = fmaxf(m, __shfl_xor(m, off));
  ax = expf(ax - m); ay = expf(ay - m); az = expf(az - m); aw = expf(aw - m);
  bx = expf(bx - m); by = expf(by - m); bz = expf(bz - m); bw = expf(bw - m);
  float s = ax + ay + az + aw + bx + by + bz + bw;
  for (int off = 32; off; off >>= 1) s += __shfl_xor(s, off);
  float inv = 1.f / s;
  ushort4 oa, ob;
  oa.x = f2b(ax * inv); oa.y = f2b(ay * inv); oa.z = f2b(az * inv); oa.w = f2b(aw * inv);
  ob.x = f2b(bx * inv); ob.y = f2b(by * inv); ob.z = f2b(bz * inv); ob.w = f2b(bw * inv);
  p[lane] = oa;
  p[lane + 64] = ob;
}

// ------------------------------ launch ------------------------------
extern "C" void kernel_launch(void* const* d_in, const int* in_sizes, int n_in,
                              void* d_out, int out_size, void* d_ws, size_t ws_size,
                              hipStream_t stream) {
  const int N = NN, E = NE;
  const float* x   = (const float*)d_in[0];
  const int*   ei  = (const int*)d_in[1];
  const float* gc  = (const float*)d_in[2];
  const float* Wp  = (const float*)d_in[3];
  const float* bp  = (const float*)d_in[4];
  const float* W1l = (const float*)d_in[5];
  const float* b1l = (const float*)d_in[6];
  const float* W1r = (const float*)d_in[7];
  const float* W2l = (const float*)d_in[8];
  const float* b2l = (const float*)d_in[9];
  const float* W2r = (const float*)d_in[10];
  const float* Wq  = (const float*)d_in[11];
  const float* bq  = (const float*)d_in[12];
  const float* Wk  = (const float*)d_in[13];
  const float* bk  = (const float*)d_in[14];
  const float* Wv  = (const float*)d_in[15];
  const float* bv  = (const float*)d_in[16];
  const float* Wm1 = (const float*)d_in[17];
  const float* bm1 = (const float*)d_in[18];
  const float* Wm2 = (const float*)d_in[19];
  const float* bm2 = (const float*)d_in[20];
  float* out = (float*)d_out;

  char* base = (char*)d_ws;
  size_t off = 0;
  auto take = [&](size_t bytes) -> void* {
    void* r = base + off;
    off += (bytes + 255) & ~(size_t)255;
    return r;
  };
  // CSR + misc
  int* cnt    = (int*)take((size_t)N * 4);
  int* rowptr = (int*)take((size_t)(N + 1) * 4);
  int* loc    = (int*)take((size_t)E * 4);
  int* eidx   = (int*)take((size_t)E * 4);
  int* eflag  = (int*)take(256);
  int* bsum   = (int*)take(NB1 * 4);
  int* boff   = (int*)take(NB1 * 4);
  // bf16 weights
  ushort* WpT   = (ushort*)take((size_t)64 * 128 * 2);
  ushort* W1lT  = (ushort*)take((size_t)256 * 64 * 2);
  ushort* W1rT  = (ushort*)take((size_t)256 * 64 * 2);
  ushort* W2lT  = (ushort*)take((size_t)256 * 256 * 2);
  ushort* W2rT  = (ushort*)take((size_t)256 * 256 * 2);
  ushort* WkT   = (ushort*)take((size_t)256 * 256 * 2);
  ushort* WvT   = (ushort*)take((size_t)256 * 256 * 2);
  ushort* Wqb   = (ushort*)take((size_t)256 * 256 * 2);
  ushort* Wm1aT = (ushort*)take((size_t)256 * 256 * 2);
  ushort* Wm1bT = (ushort*)take((size_t)256 * 256 * 2);
  // attention small
  ushort* gcb   = (ushort*)take((size_t)512 * 256 * 2);
  ushort* Kmatb = (ushort*)take((size_t)512 * 256 * 2);
  ushort* Vmatb = (ushort*)take((size_t)512 * 256 * 2);
  ushort* W_pvT = (ushort*)take((size_t)256 * 512 * 2);
  ushort* KWqT  = (ushort*)take((size_t)512 * 256 * 2);
  float*  sbias = (float*)take((size_t)512 * 4);
  // region U (full-size, single chunk): h2 [N*512B] + SP [N*1024B]; mean2
  // aliases SP lower half (dead before S written); pre-loop xb/x_emb/mean1
  // (N*512B total) fit in the h2 segment + start of SP.
  char* U = (char*)take((size_t)N * 1536);
  ushort* h = (ushort*)take((size_t)N * 256 * 2);   // live whole run
  if (off > ws_size) return;

  ushort* xb    = (ushort*)U;                           // N*256B (pre-loop)
  ushort* x_emb = (ushort*)(U + (size_t)N * 256);       // N*128B (pre-loop)
  ushort* mean1 = (ushort*)(U + (size_t)N * 384);       // N*128B (pre-loop)
  ushort* h2_c     = (ushort*)U;                        // N*512B
  ushort* SP_c     = (ushort*)(U + (size_t)N * 512);    // N*1024B (S then P)
  ushort* mean2_c  = SP_c;                              // aliases SP lower half

  const int n4 = N * 128 / 4;
  dim3 thr(256);
  dim3 thr512(512);

  // CvtJobs (Wqb pre-scaled by 1/16 to fold softmax scale)
  CvtJobs jb;
  {
    const float* s_[NJOB] = {gc, Wq, Wp, W1l, W1r, W2l, W2r, Wk, Wv, Wm1, Wm1};
    ushort* d_[NJOB] = {gcb, Wqb, WpT, W1lT, W1rT, W2lT, W2rT, WkT, WvT, Wm1aT, Wm1bT};
    int R_[NJOB] = {512, 256, 128, 64, 64, 256, 256, 256, 256, 256, 256};
    int C_[NJOB] = {256, 256, 64, 256, 256, 256, 256, 256, 256, 256, 256};
    int o_[NJOB] = {0, 0, 0, 0, 0, 0, 0, 0, 0, 0, 256};
    int t_[NJOB] = {0, 0, 1, 1, 1, 1, 1, 1, 1, 1, 1};
    for (int j = 0; j < NJOB; ++j) {
      jb.src[j] = s_[j]; jb.dst[j] = d_[j]; jb.R[j] = R_[j]; jb.C[j] = C_[j];
      jb.off[j] = o_[j]; jb.tr[j] = t_[j]; jb.sc[j] = (j == 1) ? 0.0625f : 1.0f;
    }
  }

  // CSR build + all conversions (count/x-cvt interleaved 1:4, w-cvt tail)
  zero_detect_k<<<1 + (N + 255) / 256, thr, 0, stream>>>(ei, eflag, cnt, N);
  count_cvt_k<<<CNTB + XCVB + WCVB, thr, 0, stream>>>(ei, eflag, cnt, loc, x, xb, E, n4, jb);
  // stage2: scan1 | Kmat | Vmat | embed (all depend only on count_cvt)
  stage2_k<<<16 + EMB_MB + NB1, thr, 0, stream>>>(
      cnt, rowptr, bsum, gcb, WkT, bk, Kmatb, WvT, bv, Vmatb, xb, WpT, bp, x_emb);
  // stage3: scan2 | KWqT | W_pv | sbias (all depend only on stage2)
  stage3_k<<<145, thr, 0, stream>>>(
      Kmatb, Wqb, KWqT, Wm1bT, Vmatb, W_pvT, bq, sbias, bsum, boff);
  scan3_k<<<(N + 255) / 256, thr, 0, stream>>>(rowptr, boff, N);
  fill_edges_k<<<(E + 255) / 256, thr, 0, stream>>>(ei, eflag, rowptr, loc, eidx, E);

  // SAGE1 (8-wave BM=128/BK=32 shape; bn on grid.x, bm on grid.y)
  agg64_k<<<(N + 3) / 4, thr, 0, stream>>>(x_emb, rowptr, eidx, mean1, 0, N);
  gemm64_k<true><<<dim3(1, (N + 127) / 128), thr512, 0, stream>>>(
      mean1, W1lT, 64, x_emb, W1rT, 64, b1l, h, N, 256);

  // single-pass SAGE2 + attention + fused MLP/out (PV folded via W_pv)
  {
    const int CRc = N;
    const int MBc128 = (CRc + 127) / 128;
    agg256_k<<<(CRc + 3) / 4, thr, 0, stream>>>(h, rowptr, eidx, mean2_c, 0, CRc);
    gemm64_k<false><<<dim3(1, MBc128), thr512, 0, stream>>>(
        mean2_c, W2lT, 256, h, W2rT, 256, b2l, h2_c, CRc, 256);
    gemm64_k<false><<<dim3(2, MBc128), thr512, 0, stream>>>(
        h2_c, KWqT, 256, nullptr, nullptr, 0, sbias, SP_c, CRc, 512);
    softmax_k<<<(CRc + 3) / 4, thr, 0, stream>>>(SP_c, CRc);
    mlp_out_k<<<dim3(MBc128, 1), thr512, 0, stream>>>(
        h2_c, Wm1aT, 256, SP_c, W_pvT, 512, bm1, Wm2, bm2, out, CRc);
  }
}